// Round 3
// baseline (48161.093 us; speedup 1.0000x reference)
//
#include <hip/hip_runtime.h>
#include <stdint.h>

typedef unsigned short u16;
typedef __attribute__((ext_vector_type(8))) short short8;
typedef __attribute__((ext_vector_type(4))) float f32x4;

#define NBLK 256
#define NTHR 512
#define LDS_BYTES 158144

__device__ __forceinline__ float bf2f(u16 u){
  union { unsigned int i; float f; } v; v.i = ((unsigned int)u) << 16; return v.f;
}
__device__ __forceinline__ u16 f2bf(float f){
  union { float f; unsigned int i; } v; v.f = f;
  unsigned int u = v.i;
  u += 0x7fffu + ((u >> 16) & 1u);
  return (u16)(u >> 16);
}
__device__ __forceinline__ unsigned int pk2(float a, float b){
  return (unsigned int)f2bf(a) | ((unsigned int)f2bf(b) << 16);
}
__device__ __forceinline__ float sigm(float x){ return 1.f/(1.f + expf(-x)); }

struct DP {
  const float *memory, *dec_in, *pW1, *pW2, *aWi, *aWh, *ab;
  const float *cW, *ldW, *qW, *mW, *vW, *dWi, *dWh, *db, *pjW, *pjb, *gW, *gb;
  const int* lens;
  u16 *xfrag, *h1f, *w2f, *wfA, *wfC, *ckf;
  float *pmT, *e_buf, *ah, *dh, *ctx;
  u16 *Xdyn, *Yf;
  float *aw, *awc;
  unsigned int* bar;
  float *out_mel, *out_gate, *out_align;
};

// fragment indexing: within one (chunk,mtile) block of [64 lanes][8], element for
// (row m15, k-in-chunk kk) sits at lane=(m15 | ((kk>>3)<<4)), j=kk&7
__device__ __forceinline__ int frag_off(int m15, int kk){
  return ((m15) | ((kk >> 3) << 4)) * 8 + (kk & 7);
}

// ---------------- prelude kernels ----------------

// prenet layer 1: h1[row=t*32+b][256] -> bf16 A-fragments
__global__ void k_pre1(DP p){
  int t = blockIdx.x >> 5, b = blockIdx.x & 31;
  int tid = threadIdx.x;
  __shared__ float fr[80];
  if (tid < 80) fr[tid] = (t == 0) ? 0.f : p.dec_in[(b*80 + tid)*400 + (t-1)];
  __syncthreads();
  const float* w = p.pW1 + (size_t)tid*80;
  float s = 0.f;
  #pragma unroll
  for (int m4 = 0; m4 < 20; ++m4){
    float4 wv = *(const float4*)(w + m4*4);
    s += wv.x*fr[m4*4] + wv.y*fr[m4*4+1] + wv.z*fr[m4*4+2] + wv.w*fr[m4*4+3];
  }
  s = fmaxf(s, 0.f);
  int row = blockIdx.x;            // = t*32 + b
  int rt = row >> 4, m15 = row & 15;
  int kc = tid >> 5, kk = tid & 31;
  p.h1f[(size_t)(rt*8 + kc)*512 + frag_off(m15, kk)] = f2bf(s);
}

// prenet layer 2 as MFMA GEMM: x = relu(h1 @ W2^T) -> xfrag
// NOTE: must run AFTER k_wfrag (consumes p.w2f) and k_pre1 (h1f).
__global__ void k_h2(DP p){
  int rt = blockIdx.x;
  int tid = threadIdx.x, w = tid >> 6, l = tid & 63;
  const u16* abase = p.h1f + (size_t)rt*8*512;
  short8 af[8];
  #pragma unroll
  for (int kc = 0; kc < 8; ++kc) af[kc] = *(const short8*)(abase + kc*512 + l*8);
  for (int nt = w; nt < 16; nt += 4){
    f32x4 acc = {0.f,0.f,0.f,0.f};
    #pragma unroll
    for (int kc = 0; kc < 8; ++kc){
      short8 bf = *(const short8*)(p.w2f + (size_t)((nt*8 + kc)*64 + l)*8);
      acc = __builtin_amdgcn_mfma_f32_16x16x32_bf16(af[kc], bf, acc, 0, 0, 0);
    }
    int ncol = l & 15, rg = l >> 4;
    #pragma unroll
    for (int r = 0; r < 4; ++r){
      float v = fmaxf(acc[r], 0.f);
      int row = rt*16 + rg*4 + r;
      int t = row >> 5, b = row & 31;
      int n = nt*16 + ncol;
      int ch = n >> 5, kk = n & 31, mt = b >> 4;
      p.xfrag[(size_t)((t*8 + ch)*2 + mt)*512 + frag_off(b & 15, kk)] = f2bf(v);
    }
  }
}

// processed_memory transposed: pmT[b][a][t'] = sum_e mem[b][t'][e]*mW[a][e]
__global__ void k_pm(DP p){
  int b = blockIdx.x & 31, tt = blockIdx.x >> 5;
  int tid = threadIdx.x;
  __shared__ u16 ml[32*516];
  for (int s = tid; s < 32*512; s += 512){
    int r = s >> 9, e = s & 511;
    ml[r*516 + e] = f2bf(p.memory[(size_t)((b*256) + tt*32 + r)*512 + e]);
  }
  __syncthreads();
  int a = tid >> 2, tg = tid & 3;
  const float* wr = p.mW + (size_t)a*512;
  float acc[8];
  #pragma unroll
  for (int m = 0; m < 8; ++m) acc[m] = 0.f;
  for (int e8 = 0; e8 < 64; ++e8){
    float4 w0 = *(const float4*)(wr + e8*8);
    float4 w1 = *(const float4*)(wr + e8*8 + 4);
    float wf[8] = {w0.x,w0.y,w0.z,w0.w,w1.x,w1.y,w1.z,w1.w};
    #pragma unroll
    for (int q = 0; q < 8; ++q){
      int e = e8*8 + q;
      #pragma unroll
      for (int m = 0; m < 8; ++m) acc[m] += wf[q] * bf2f(ml[(tg*8 + m)*516 + e]);
    }
  }
  float* dst = p.pmT + (size_t)(b*128 + a)*256 + tt*32 + tg*8;
  f32x4 v0 = {acc[0],acc[1],acc[2],acc[3]}, v1 = {acc[4],acc[5],acc[6],acc[7]};
  *(f32x4*)dst = v0; *(f32x4*)(dst + 4) = v1;
}

// combined location kernel CK[a][c][k] = sum_f ldW[a,f]*cW[f,c,k], packed as MFMA B-frag.
// 8 slices of 16 att-dims each: slice rr covers a in [rr*16, rr*16+16).
// K-packing: k in [0,31): c=0 tap k; k==31: 0; k in [32,63): c=1 tap k-32; k==63: 0
__global__ void k_ck(DP p){
  int s = blockIdx.x*512 + threadIdx.x;   // 0..8191
  if (s >= 8192) return;
  int slice = s >> 10;
  int rem = s & 1023;
  int l = (rem >> 3) & 63, j = rem & 7, kc = rem >> 9;
  int a = slice*16 + (l & 15), k = kc*32 + ((l >> 4) << 3) + j;
  float val = 0.f;
  if (k != 31 && k != 63){
    int c = (k >= 32) ? 1 : 0, tap = k - (c ? 32 : 0);
    for (int f = 0; f < 32; ++f)
      val += p.ldW[a*32 + f] * p.cW[(f*2 + c)*31 + tap];
  }
  p.ckf[s] = f2bf(val);
}

// weight fragment gather (f32 -> bf16) for att GEMM, dec GEMM, prenet W2
__global__ void k_wfrag(DP p){
  int g = blockIdx.x*512 + threadIdx.x;
  const int GA = 256*56*64;        // 917504
  const int GC = 256*80*64;        // 1310720
  const float* src;
  u16* dst;
  if (g < GA){
    int j = g / (56*64); int rem = g - j*56*64; int ch = rem >> 6; int l = rem & 63;
    int c = l & 15, R = ((c >> 2) << 10) + j*4 + (c & 3);
    int k0 = ch*32 + ((l >> 4) << 3);
    src = (k0 < 768) ? (p.aWi + (size_t)R*768 + k0) : (p.aWh + (size_t)R*1024 + (k0 - 768));
    dst = p.wfA + (size_t)g*8;
  } else if (g < GA + GC){
    int g2 = g - GA;
    int j = g2 / (80*64); int rem = g2 - j*80*64; int ch = rem >> 6; int l = rem & 63;
    int c = l & 15, R = ((c >> 2) << 10) + j*4 + (c & 3);
    int k0 = ch*32 + ((l >> 4) << 3);
    src = (k0 < 1536) ? (p.dWi + (size_t)R*1536 + k0) : (p.dWh + (size_t)R*1024 + (k0 - 1536));
    dst = p.wfC + (size_t)g2*8;
  } else {
    int g3 = g - GA - GC;            // < 8192
    int nt = g3 >> 9; int rem = g3 & 511; int kc = rem >> 6; int l = rem & 63;
    src = p.pW2 + (size_t)(nt*16 + (l & 15))*256 + kc*32 + ((l >> 4) << 3);
    dst = p.w2f + (size_t)g3*8;
  }
  float4 v0 = *(const float4*)src;
  float4 v1 = *(const float4*)(src + 4);
  uint4 o;
  o.x = pk2(v0.x, v0.y); o.y = pk2(v0.z, v0.w);
  o.z = pk2(v1.x, v1.y); o.w = pk2(v1.z, v1.w);
  *(uint4*)dst = o;
}

// ---------------- grid barrier ----------------
__device__ __forceinline__ void gbar(unsigned int* bar, unsigned int ep){
  __syncthreads();
  if (threadIdx.x == 0){
    unsigned int prev = __hip_atomic_fetch_add(&bar[0], 1u, __ATOMIC_ACQ_REL, __HIP_MEMORY_SCOPE_AGENT);
    if (prev == (unsigned int)(NBLK - 1)){
      __hip_atomic_store(&bar[0], 0u, __ATOMIC_RELAXED, __HIP_MEMORY_SCOPE_AGENT);
      __hip_atomic_store(&bar[1], ep, __ATOMIC_RELEASE, __HIP_MEMORY_SCOPE_AGENT);
    } else {
      while (__hip_atomic_load(&bar[1], __ATOMIC_ACQUIRE, __HIP_MEMORY_SCOPE_AGENT) < ep) { }
    }
  }
  __syncthreads();
}

// ---------------- persistent decoder ----------------
__launch_bounds__(NTHR, 2)
__global__ void k_decoder(DP p){
  extern __shared__ char smem[];
  u16*   wA     = (u16*)smem;                    // 57344 B: att weight frags (16 cols)
  u16*   wC     = (u16*)(smem + 57344);          // 81920 B: dec weight frags
  float* bias_l = (float*)(smem + 139264);       // 32 f32
  char*  uni    = smem + 139392;                 // 18752 B phase-union
  float* redA  = (float*)uni;                    // CA: 4 waves x 2mt x 16c x 16b
  float* redC  = (float*)(uni + 8192);
  float* aw_l  = (float*)uni;                    // B1: [2][288] padded aw/aw_cum
  float* q_l   = (float*)(uni + 2304);           // B1: 16 f32
  u16*   im2   = (u16*)(uni + 2368);             // B1: 16384 B im2col A-frags
  float* e_l   = (float*)uni;                    // B2
  float* r_l   = (float*)(uni + 1024);
  float* awn_l = (float*)(uni + 1088);

  const int blk = blockIdx.x;
  const int tid = threadIdx.x;
  const int bb = blk & 31, rr = blk >> 5;        // batch / role within batch group
  const int w = tid >> 6, l = tid & 63;

  { // load persistent weights into LDS
    const uint4* s  = (const uint4*)(p.wfA + (size_t)blk*56*512);
    uint4* d = (uint4*)wA;
    for (int i2 = tid; i2 < 3584; i2 += NTHR) d[i2] = s[i2];
    const uint4* s2 = (const uint4*)(p.wfC + (size_t)blk*80*512);
    uint4* d2 = (uint4*)wC;
    for (int i2 = tid; i2 < 5120; i2 += NTHR) d2[i2] = s2[i2];
    if (tid < 16){
      int R = ((tid >> 2) << 10) + blk*4 + (tid & 3);
      bias_l[tid] = p.ab[R];
    } else if (tid < 32){
      int c = tid - 16;
      int R = ((c >> 2) << 10) + blk*4 + (c & 3);
      bias_l[tid] = p.db[R];
    }
  }
  __syncthreads();

  float att_c = 0.f, dec_c = 0.f;    // persistent cell states (tid<128 att, 128..255 dec)
  unsigned int ep = 0;

  for (int i = 0; i <= 400; ++i){
    const bool hasA = (i < 400), hasC = (i > 0);

    // ================= phase CA: A(i) on waves 0-3, C(i-1) on waves 4-7 =================
    if (hasA && w < 4){
      f32x4 acc0 = {0.f,0.f,0.f,0.f}, acc1 = {0.f,0.f,0.f,0.f};
      const u16* xd = p.Xdyn + (size_t)(i & 1)*48*2*512;
      const u16* xs = p.xfrag + (size_t)i*8*2*512;
      for (int c = w*14; c < w*14 + 14; ++c){
        short8 bfr = *(const short8*)(wA + (c*64 + l)*8);
        const u16* abase = (c < 8) ? (xs + (size_t)c*2*512) : (xd + (size_t)(c - 8)*2*512);
        short8 a0 = *(const short8*)(abase + l*8);
        short8 a1 = *(const short8*)(abase + 512 + l*8);
        acc0 = __builtin_amdgcn_mfma_f32_16x16x32_bf16(a0, bfr, acc0, 0, 0, 0);
        acc1 = __builtin_amdgcn_mfma_f32_16x16x32_bf16(a1, bfr, acc1, 0, 0, 0);
      }
      int cc = l & 15, rg = l >> 4;
      *(f32x4*)(redA + (((w*2 + 0)*16 + cc) << 4) + (rg << 2)) = acc0;
      *(f32x4*)(redA + (((w*2 + 1)*16 + cc) << 4) + (rg << 2)) = acc1;
    }
    if (hasC && w >= 4){
      f32x4 acc0 = {0.f,0.f,0.f,0.f}, acc1 = {0.f,0.f,0.f,0.f};
      const u16* yb = p.Yf + (size_t)((i + 1) & 1)*80*2*512;
      for (int c = (w - 4)*20; c < (w - 4)*20 + 20; ++c){
        short8 bfr = *(const short8*)(wC + (c*64 + l)*8);
        short8 a0 = *(const short8*)(yb + (size_t)c*2*512 + l*8);
        short8 a1 = *(const short8*)(yb + (size_t)c*2*512 + 512 + l*8);
        acc0 = __builtin_amdgcn_mfma_f32_16x16x32_bf16(a0, bfr, acc0, 0, 0, 0);
        acc1 = __builtin_amdgcn_mfma_f32_16x16x32_bf16(a1, bfr, acc1, 0, 0, 0);
      }
      int cc = l & 15, rg = l >> 4, w4 = w - 4;
      *(f32x4*)(redC + (((w4*2 + 0)*16 + cc) << 4) + (rg << 2)) = acc0;
      *(f32x4*)(redC + (((w4*2 + 1)*16 + cc) << 4) + (rg << 2)) = acc1;
    }
    __syncthreads();
    if (hasA && tid < 128){   // att LSTM state update for (b, d); this block owns dims blk*4+d
      int b = tid >> 2, d = tid & 3, mt = b >> 4, b15 = b & 15;
      float gi = bias_l[d], gf = bias_l[4 + d], gg = bias_l[8 + d], go = bias_l[12 + d];
      #pragma unroll
      for (int w2 = 0; w2 < 4; ++w2){
        const float* base = redA + (((w2*2 + mt)*16) << 4) + b15;
        gi += base[(d) << 4]; gf += base[(4 + d) << 4];
        gg += base[(8 + d) << 4]; go += base[(12 + d) << 4];
      }
      att_c = sigm(gf)*att_c + sigm(gi)*tanhf(gg);
      float h = sigm(go)*tanhf(att_c);
      int hidx = blk*4 + d;
      p.ah[b*1024 + hidx] = h;
      u16 hb = f2bf(h);
      { int k = hidx, ch = k >> 5, kk = k & 31;
        p.Yf[(size_t)(((i & 1)*80 + ch)*2 + mt)*512 + frag_off(b15, kk)] = hb; }
      { int k = 768 + hidx, ch = (k >> 5) - 8, kk = k & 31;
        p.Xdyn[(size_t)((((i + 1) & 1)*48 + ch)*2 + mt)*512 + frag_off(b15, kk)] = hb; }
    }
    if (hasC && tid >= 128 && tid < 256){   // dec LSTM state update (step i-1)
      int t2 = tid - 128;
      int b = t2 >> 2, d = t2 & 3, mt = b >> 4, b15 = b & 15;
      float gi = bias_l[16 + d], gf = bias_l[16 + 4 + d], gg = bias_l[16 + 8 + d], go = bias_l[16 + 12 + d];
      #pragma unroll
      for (int w2 = 0; w2 < 4; ++w2){
        const float* base = redC + (((w2*2 + mt)*16) << 4) + b15;
        gi += base[(d) << 4]; gf += base[(4 + d) << 4];
        gg += base[(8 + d) << 4]; go += base[(12 + d) << 4];
      }
      dec_c = sigm(gf)*dec_c + sigm(gi)*tanhf(gg);
      float h = sigm(go)*tanhf(dec_c);
      int hidx = blk*4 + d;
      p.dh[b*1024 + hidx] = h;
      u16 hb = f2bf(h);
      { int k = 1536 + hidx, ch = k >> 5, kk = k & 31;
        p.Yf[(size_t)(((i & 1)*80 + ch)*2 + mt)*512 + frag_off(b15, kk)] = hb; }
    }
    gbar(p.bar, ++ep);

    // ================= phase B1: q-slice + energies (+ projection of step i-1) ==========
    if (hasA){
      for (int s = tid; s < 576; s += NTHR){
        int c = s / 288, o = s - c*288;
        float v2 = 0.f;
        if (o >= 16 && o < 272) v2 = c ? p.awc[bb*256 + (o - 16)] : p.aw[bb*256 + (o - 16)];
        aw_l[s] = v2;
      }
      { // q slice for a in [rr*16, rr*16+16)
        int asub = tid >> 5, ksub = tid & 31;
        const float* qwr = p.qW + (size_t)(rr*16 + asub)*1024;
        const float* ahr = p.ah + bb*1024;
        float s = 0.f;
        for (int m = 0; m < 32; ++m){
          int k = ksub + (m << 5);
          s += qwr[k] * ahr[k];
        }
        s += __shfl_xor(s, 16, 32); s += __shfl_xor(s, 8, 32);
        s += __shfl_xor(s, 4, 32);  s += __shfl_xor(s, 2, 32); s += __shfl_xor(s, 1, 32);
        if (ksub == 0) q_l[asub] = s;
      }
      __syncthreads();
      #pragma unroll 1
      for (int hh = 0; hh < 2; ++hh){     // two t'-halves of 128
        for (int s = tid; s < 8192; s += NTHR){
          int jj = s & 7, ll = (s >> 3) & 63, kc = (s >> 9) & 1, mt = s >> 10;
          int trow = hh*128 + mt*16 + (ll & 15);
          int k = kc*32 + ((ll >> 4) << 3) + jj;
          float v2 = 0.f;
          if (k < 31) v2 = aw_l[1 + trow + k];
          else if (k >= 32 && k < 63) v2 = aw_l[289 + trow + (k - 32)];
          im2[s] = f2bf(v2);
        }
        __syncthreads();
        {
          f32x4 acc = {0.f,0.f,0.f,0.f};
          short8 a0 = *(const short8*)(im2 + ((w*2 + 0)*64 + l)*8);
          short8 b0 = *(const short8*)(p.ckf + (size_t)rr*1024 + (0*64 + l)*8);
          short8 a1 = *(const short8*)(im2 + ((w*2 + 1)*64 + l)*8);
          short8 b1 = *(const short8*)(p.ckf + (size_t)rr*1024 + (1*64 + l)*8);
          acc = __builtin_amdgcn_mfma_f32_16x16x32_bf16(a0, b0, acc, 0, 0, 0);
          acc = __builtin_amdgcn_mfma_f32_16x16x32_bf16(a1, b1, acc, 0, 0, 0);
          int a_l = l & 15, rg = l >> 4;
          float q_a = q_l[a_l];
          float va = p.vW[rr*16 + a_l];
          int tbase = hh*128 + w*16 + rg*4;
          const float* pmr = p.pmT + (size_t)(bb*128 + rr*16 + a_l)*256 + tbase;
          f32x4 pv = *(const f32x4*)pmr;
          float e0 = va * tanhf(acc[0] + q_a + pv[0]);
          float e1 = va * tanhf(acc[1] + q_a + pv[1]);
          float e2 = va * tanhf(acc[2] + q_a + pv[2]);
          float e3 = va * tanhf(acc[3] + q_a + pv[3]);
          #pragma unroll
          for (int msk = 8; msk >= 1; msk >>= 1){
            e0 += __shfl_xor(e0, msk, 16);
            e1 += __shfl_xor(e1, msk, 16);
            e2 += __shfl_xor(e2, msk, 16);
            e3 += __shfl_xor(e3, msk, 16);
          }
          if (a_l == 0){
            f32x4 evv = {e0, e1, e2, e3};
            *(f32x4*)(p.e_buf + (size_t)(bb*8 + rr)*256 + tbase) = evv;
          }
        }
        __syncthreads();
      }
    }
    if (hasC){   // projection for step i-1 (rows rr*10.., gate row = 80)
      int grp = tid >> 5, gl = tid & 31;
      int cnt = (rr == 7) ? 11 : 10;
      if (grp < cnt){
        int r = rr*10 + grp;
        const float* wrow = (r < 80) ? (p.pjW + (size_t)r*1536) : p.gW;
        const float* dhr = p.dh + bb*1024;
        const float* cxr = p.ctx + bb*512;
        float s = 0.f;
        for (int k = gl; k < 1024; k += 32) s += wrow[k] * dhr[k];
        for (int k = gl; k < 512;  k += 32) s += wrow[1024 + k] * cxr[k];
        s += __shfl_xor(s, 16, 32); s += __shfl_xor(s, 8, 32);
        s += __shfl_xor(s, 4, 32);  s += __shfl_xor(s, 2, 32); s += __shfl_xor(s, 1, 32);
        if (gl == 0){
          if (r < 80) p.out_mel[(size_t)(bb*80 + r)*400 + (i - 1)] = s + p.pjb[r];
          else        p.out_gate[bb*400 + (i - 1)] = s + p.gb[0];
        }
      }
    }
    if (i == 400) break;
    gbar(p.bar, ++ep);

    // ================= phase B2: softmax (redundant per rr) + ctx slice ==================
    {
      int len = p.lens[bb];
      if (tid < 256){
        float s = 0.f;
        #pragma unroll
        for (int r2 = 0; r2 < 8; ++r2) s += p.e_buf[(size_t)(bb*8 + r2)*256 + tid];
        if (tid >= len) s = -1e9f;
        e_l[tid] = s;
      }
      __syncthreads();
      float v2 = (tid < 256) ? e_l[tid] : -3.0e38f;
      #pragma unroll
      for (int off = 32; off >= 1; off >>= 1) v2 = fmaxf(v2, __shfl_xor(v2, off, 64));
      if ((tid & 63) == 0) r_l[tid >> 6] = v2;
      __syncthreads();
      if (tid == 0){
        float m2 = r_l[0];
        #pragma unroll
        for (int w2 = 1; w2 < 8; ++w2) m2 = fmaxf(m2, r_l[w2]);
        r_l[8] = m2;
      }
      __syncthreads();
      float mx = r_l[8];
      float exv = (tid < 256) ? expf(e_l[tid] - mx) : 0.f;
      float sv = exv;
      #pragma unroll
      for (int off = 32; off >= 1; off >>= 1) sv += __shfl_xor(sv, off, 64);
      if ((tid & 63) == 0) r_l[tid >> 6] = sv;
      __syncthreads();
      if (tid == 0){
        float ss = 0.f;
        #pragma unroll
        for (int w2 = 0; w2 < 8; ++w2) ss += r_l[w2];
        r_l[9] = 1.f / ss;
      }
      __syncthreads();
      float awn = exv * r_l[9];
      if (tid < 256){
        awn_l[tid] = awn;
        if (rr == 0){
          p.aw[bb*256 + tid] = awn;
          p.awc[bb*256 + tid] += awn;
          p.out_align[(size_t)(bb*400 + i)*256 + tid] = awn;
        }
      }
      __syncthreads();
      { // ctx slice e' in [rr*64, rr*64+64)
        int el = rr*64 + (tid >> 3), g = tid & 7;
        const float* mr = p.memory + (size_t)bb*256*512 + el;
        float s2 = 0.f;
        for (int t2 = g; t2 < 256; t2 += 8) s2 += awn_l[t2] * mr[(size_t)t2*512];
        s2 += __shfl_xor(s2, 4, 8); s2 += __shfl_xor(s2, 2, 8); s2 += __shfl_xor(s2, 1, 8);
        if (g == 0){
          p.ctx[bb*512 + el] = s2;
          u16 cb = f2bf(s2);
          int mt = bb >> 4, b15 = bb & 15;
          { int k = 1024 + el, ch = k >> 5, kk = k & 31;
            p.Yf[(size_t)(((i & 1)*80 + ch)*2 + mt)*512 + frag_off(b15, kk)] = cb; }
          { int k = 256 + el, ch = (k >> 5) - 8, kk = k & 31;
            p.Xdyn[(size_t)((((i + 1) & 1)*48 + ch)*2 + mt)*512 + frag_off(b15, kk)] = cb; }
        }
      }
    }
    gbar(p.bar, ++ep);
  }
}

// ---------------- host ----------------
extern "C" void kernel_launch(void* const* d_in, const int* in_sizes, int n_in,
                              void* d_out, int out_size, void* d_ws, size_t ws_size,
                              hipStream_t stream){
  (void)in_sizes; (void)n_in; (void)out_size; (void)ws_size;
  DP p;
  p.memory = (const float*)d_in[0];
  p.dec_in = (const float*)d_in[1];
  p.lens   = (const int*)d_in[2];
  p.pW1 = (const float*)d_in[3];  p.pW2 = (const float*)d_in[4];
  p.aWi = (const float*)d_in[5];  p.aWh = (const float*)d_in[6];  p.ab = (const float*)d_in[7];
  p.cW  = (const float*)d_in[8];  p.ldW = (const float*)d_in[9];  p.qW = (const float*)d_in[10];
  p.mW  = (const float*)d_in[11]; p.vW  = (const float*)d_in[12];
  p.dWi = (const float*)d_in[13]; p.dWh = (const float*)d_in[14]; p.db = (const float*)d_in[15];
  p.pjW = (const float*)d_in[16]; p.pjb = (const float*)d_in[17];
  p.gW  = (const float*)d_in[18]; p.gb  = (const float*)d_in[19];

  char* ws = (char*)d_ws;
  size_t o = 0;
  auto take = [&](size_t bytes)->char*{ char* r = ws + o; o += (bytes + 255) & ~(size_t)255; return r; };
  p.xfrag = (u16*)take((size_t)3276800*2);
  p.h1f   = (u16*)take((size_t)3276800*2);
  p.w2f   = (u16*)take((size_t)65536*2);
  p.wfA   = (u16*)take((size_t)7340032*2);
  p.wfC   = (u16*)take((size_t)10485760*2);
  p.ckf   = (u16*)take((size_t)8192*2);
  p.pmT   = (float*)take((size_t)1048576*4);
  p.e_buf = (float*)take((size_t)65536*4);
  p.ah    = (float*)take((size_t)32768*4);
  p.dh    = (float*)take((size_t)32768*4);
  p.ctx   = (float*)take((size_t)16384*4);
  char* z0 = ws + o;                     // zero-init region
  p.Xdyn  = (u16*)take((size_t)98304*2);
  p.Yf    = (u16*)take((size_t)163840*2);
  p.aw    = (float*)take((size_t)8192*4);
  p.awc   = (float*)take((size_t)8192*4);
  p.bar   = (unsigned int*)take(256);
  size_t zbytes = (size_t)((ws + o) - z0);

  float* out = (float*)d_out;
  p.out_mel   = out;
  p.out_gate  = out + 1024000;
  p.out_align = out + 1036800;

  hipMemsetAsync(z0, 0, zbytes, stream);
  // order matters: k_h2 consumes w2f (from k_wfrag) and h1f (from k_pre1)
  k_pre1 <<<dim3(12800), dim3(256), 0, stream>>>(p);
  k_wfrag<<<dim3(4368),  dim3(512), 0, stream>>>(p);
  k_ck   <<<dim3(16),    dim3(512), 0, stream>>>(p);
  k_pm   <<<dim3(256),   dim3(512), 0, stream>>>(p);
  k_h2   <<<dim3(800),   dim3(256), 0, stream>>>(p);

  hipFuncSetAttribute(reinterpret_cast<const void*>(k_decoder),
                      hipFuncAttributeMaxDynamicSharedMemorySize, LDS_BYTES);
  DP pp = p;
  void* args[] = { &pp };
  hipError_t err = hipLaunchCooperativeKernel(reinterpret_cast<void*>(k_decoder),
                                              dim3(NBLK), dim3(NTHR), args,
                                              (unsigned int)LDS_BYTES, stream);
  if (err != hipSuccess){
    // co-residency still guaranteed: 256 blocks, 158KB LDS -> exactly 1 block/CU on 256 CUs
    k_decoder<<<dim3(NBLK), dim3(NTHR), LDS_BYTES, stream>>>(pp);
  }
}

// Round 4
// 24959.024 us; speedup vs baseline: 1.9296x; 1.9296x over previous
//
#include <hip/hip_runtime.h>
#include <stdint.h>

typedef unsigned short u16;
typedef __attribute__((ext_vector_type(8))) short short8;
typedef __attribute__((ext_vector_type(4))) float f32x4;

#define NBLK 256
#define NTHR 512
#define LDS_BYTES 158144

__device__ __forceinline__ float bf2f(u16 u){
  union { unsigned int i; float f; } v; v.i = ((unsigned int)u) << 16; return v.f;
}
__device__ __forceinline__ u16 f2bf(float f){
  union { float f; unsigned int i; } v; v.f = f;
  unsigned int u = v.i;
  u += 0x7fffu + ((u >> 16) & 1u);
  return (u16)(u >> 16);
}
__device__ __forceinline__ unsigned int pk2(float a, float b){
  return (unsigned int)f2bf(a) | ((unsigned int)f2bf(b) << 16);
}
__device__ __forceinline__ float sigm(float x){ return 1.f/(1.f + expf(-x)); }

struct DP {
  const float *memory, *dec_in, *pW1, *pW2, *aWi, *aWh, *ab;
  const float *cW, *ldW, *qW, *mW, *vW, *dWi, *dWh, *db, *pjW, *pjb, *gW, *gb;
  const int* lens;
  u16 *xfrag, *h1f, *w2f, *wfA, *wfC, *ckf;
  float *pmT, *e_buf, *ah, *dh, *ctx;
  u16 *Xdyn, *Yf;
  float *aw, *awc;
  unsigned int* bar;     // 256 slots, 64B apart (u32 index stride 16)
  float *out_mel, *out_gate, *out_align;
};

// fragment indexing: within one (chunk,mtile) block of [64 lanes][8], element for
// (row m15, k-in-chunk kk) sits at lane=(m15 | ((kk>>3)<<4)), j=kk&7
__device__ __forceinline__ int frag_off(int m15, int kk){
  return ((m15) | ((kk >> 3) << 4)) * 8 + (kk & 7);
}

// ---------------- prelude kernels ----------------

// prenet layer 1: h1[row=t*32+b][256] -> bf16 A-fragments
__global__ void k_pre1(DP p){
  int t = blockIdx.x >> 5, b = blockIdx.x & 31;
  int tid = threadIdx.x;
  __shared__ float fr[80];
  if (tid < 80) fr[tid] = (t == 0) ? 0.f : p.dec_in[(b*80 + tid)*400 + (t-1)];
  __syncthreads();
  const float* w = p.pW1 + (size_t)tid*80;
  float s = 0.f;
  #pragma unroll
  for (int m4 = 0; m4 < 20; ++m4){
    float4 wv = *(const float4*)(w + m4*4);
    s += wv.x*fr[m4*4] + wv.y*fr[m4*4+1] + wv.z*fr[m4*4+2] + wv.w*fr[m4*4+3];
  }
  s = fmaxf(s, 0.f);
  int row = blockIdx.x;            // = t*32 + b
  int rt = row >> 4, m15 = row & 15;
  int kc = tid >> 5, kk = tid & 31;
  p.h1f[(size_t)(rt*8 + kc)*512 + frag_off(m15, kk)] = f2bf(s);
}

// prenet layer 2 as MFMA GEMM: x = relu(h1 @ W2^T) -> xfrag
// NOTE: must run AFTER k_wfrag (consumes p.w2f) and k_pre1 (h1f).
__global__ void k_h2(DP p){
  int rt = blockIdx.x;
  int tid = threadIdx.x, w = tid >> 6, l = tid & 63;
  const u16* abase = p.h1f + (size_t)rt*8*512;
  short8 af[8];
  #pragma unroll
  for (int kc = 0; kc < 8; ++kc) af[kc] = *(const short8*)(abase + kc*512 + l*8);
  for (int nt = w; nt < 16; nt += 4){
    f32x4 acc = {0.f,0.f,0.f,0.f};
    #pragma unroll
    for (int kc = 0; kc < 8; ++kc){
      short8 bf = *(const short8*)(p.w2f + (size_t)((nt*8 + kc)*64 + l)*8);
      acc = __builtin_amdgcn_mfma_f32_16x16x32_bf16(af[kc], bf, acc, 0, 0, 0);
    }
    int ncol = l & 15, rg = l >> 4;
    #pragma unroll
    for (int r = 0; r < 4; ++r){
      float v = fmaxf(acc[r], 0.f);
      int row = rt*16 + rg*4 + r;
      int t = row >> 5, b = row & 31;
      int n = nt*16 + ncol;
      int ch = n >> 5, kk = n & 31, mt = b >> 4;
      p.xfrag[(size_t)((t*8 + ch)*2 + mt)*512 + frag_off(b & 15, kk)] = f2bf(v);
    }
  }
}

// processed_memory transposed: pmT[b][a][t'] = sum_e mem[b][t'][e]*mW[a][e]
__global__ void k_pm(DP p){
  int b = blockIdx.x & 31, tt = blockIdx.x >> 5;
  int tid = threadIdx.x;
  __shared__ u16 ml[32*516];
  for (int s = tid; s < 32*512; s += 512){
    int r = s >> 9, e = s & 511;
    ml[r*516 + e] = f2bf(p.memory[(size_t)((b*256) + tt*32 + r)*512 + e]);
  }
  __syncthreads();
  int a = tid >> 2, tg = tid & 3;
  const float* wr = p.mW + (size_t)a*512;
  float acc[8];
  #pragma unroll
  for (int m = 0; m < 8; ++m) acc[m] = 0.f;
  for (int e8 = 0; e8 < 64; ++e8){
    float4 w0 = *(const float4*)(wr + e8*8);
    float4 w1 = *(const float4*)(wr + e8*8 + 4);
    float wf[8] = {w0.x,w0.y,w0.z,w0.w,w1.x,w1.y,w1.z,w1.w};
    #pragma unroll
    for (int q = 0; q < 8; ++q){
      int e = e8*8 + q;
      #pragma unroll
      for (int m = 0; m < 8; ++m) acc[m] += wf[q] * bf2f(ml[(tg*8 + m)*516 + e]);
    }
  }
  float* dst = p.pmT + (size_t)(b*128 + a)*256 + tt*32 + tg*8;
  f32x4 v0 = {acc[0],acc[1],acc[2],acc[3]}, v1 = {acc[4],acc[5],acc[6],acc[7]};
  *(f32x4*)dst = v0; *(f32x4*)(dst + 4) = v1;
}

// combined location kernel CK[a][c][k] = sum_f ldW[a,f]*cW[f,c,k], packed as MFMA B-frag.
// 8 slices of 16 att-dims each: slice rr covers a in [rr*16, rr*16+16).
// K-packing: k in [0,31): c=0 tap k; k==31: 0; k in [32,63): c=1 tap k-32; k==63: 0
__global__ void k_ck(DP p){
  int s = blockIdx.x*512 + threadIdx.x;   // 0..8191
  if (s >= 8192) return;
  int slice = s >> 10;
  int rem = s & 1023;
  int l = (rem >> 3) & 63, j = rem & 7, kc = rem >> 9;
  int a = slice*16 + (l & 15), k = kc*32 + ((l >> 4) << 3) + j;
  float val = 0.f;
  if (k != 31 && k != 63){
    int c = (k >= 32) ? 1 : 0, tap = k - (c ? 32 : 0);
    for (int f = 0; f < 32; ++f)
      val += p.ldW[a*32 + f] * p.cW[(f*2 + c)*31 + tap];
  }
  p.ckf[s] = f2bf(val);
}

// weight fragment gather (f32 -> bf16) for att GEMM, dec GEMM, prenet W2
__global__ void k_wfrag(DP p){
  int g = blockIdx.x*512 + threadIdx.x;
  const int GA = 256*56*64;        // 917504
  const int GC = 256*80*64;        // 1310720
  const float* src;
  u16* dst;
  if (g < GA){
    int j = g / (56*64); int rem = g - j*56*64; int ch = rem >> 6; int l = rem & 63;
    int c = l & 15, R = ((c >> 2) << 10) + j*4 + (c & 3);
    int k0 = ch*32 + ((l >> 4) << 3);
    src = (k0 < 768) ? (p.aWi + (size_t)R*768 + k0) : (p.aWh + (size_t)R*1024 + (k0 - 768));
    dst = p.wfA + (size_t)g*8;
  } else if (g < GA + GC){
    int g2 = g - GA;
    int j = g2 / (80*64); int rem = g2 - j*80*64; int ch = rem >> 6; int l = rem & 63;
    int c = l & 15, R = ((c >> 2) << 10) + j*4 + (c & 3);
    int k0 = ch*32 + ((l >> 4) << 3);
    src = (k0 < 1536) ? (p.dWi + (size_t)R*1536 + k0) : (p.dWh + (size_t)R*1024 + (k0 - 1536));
    dst = p.wfC + (size_t)g2*8;
  } else {
    int g3 = g - GA - GC;            // < 8192
    int nt = g3 >> 9; int rem = g3 & 511; int kc = rem >> 6; int l = rem & 63;
    src = p.pW2 + (size_t)(nt*16 + (l & 15))*256 + kc*32 + ((l >> 4) << 3);
    dst = p.w2f + (size_t)g3*8;
  }
  float4 v0 = *(const float4*)src;
  float4 v1 = *(const float4*)(src + 4);
  uint4 o;
  o.x = pk2(v0.x, v0.y); o.y = pk2(v0.z, v0.w);
  o.z = pk2(v1.x, v1.y); o.w = pk2(v1.z, v1.w);
  *(uint4*)dst = o;
}

// ---------------- grid barrier (all-poll, contention-free) ----------------
// Each block owns one 64B-separated epoch slot. Arrival = one release store
// (no RMW -> no same-line serialization). Wave 0 polls all 256 slots (4 per
// lane, relaxed agent loads, all in flight), then one acquire fence performs
// the CU-wide L1/L2 invalidate before __syncthreads releases the other waves.
__device__ __forceinline__ void gbar(unsigned int* slots, unsigned int ep){
  __syncthreads();
  if (threadIdx.x == 0){
    __hip_atomic_store(&slots[blockIdx.x << 4], ep, __ATOMIC_RELEASE, __HIP_MEMORY_SCOPE_AGENT);
  }
  if (threadIdx.x < 64){
    const int base = threadIdx.x << 2;
    for (;;){
      unsigned int a = __hip_atomic_load(&slots[(base + 0) << 4], __ATOMIC_RELAXED, __HIP_MEMORY_SCOPE_AGENT);
      unsigned int b = __hip_atomic_load(&slots[(base + 1) << 4], __ATOMIC_RELAXED, __HIP_MEMORY_SCOPE_AGENT);
      unsigned int c = __hip_atomic_load(&slots[(base + 2) << 4], __ATOMIC_RELAXED, __HIP_MEMORY_SCOPE_AGENT);
      unsigned int d = __hip_atomic_load(&slots[(base + 3) << 4], __ATOMIC_RELAXED, __HIP_MEMORY_SCOPE_AGENT);
      bool ok = (a >= ep) & (b >= ep) & (c >= ep) & (d >= ep);
      if (__all(ok)) break;
    }
    __builtin_amdgcn_fence(__ATOMIC_ACQUIRE, "agent");
  }
  __syncthreads();
}

// ---------------- persistent decoder ----------------
__launch_bounds__(NTHR, 2)
__global__ void k_decoder(DP p){
  extern __shared__ char smem[];
  u16*   wA     = (u16*)smem;                    // 57344 B: att weight frags (16 cols)
  u16*   wC     = (u16*)(smem + 57344);          // 81920 B: dec weight frags
  float* bias_l = (float*)(smem + 139264);       // 32 f32
  char*  uni    = smem + 139392;                 // 18752 B phase-union
  float* redA  = (float*)uni;                    // CA: 4 waves x 2mt x 16c x 16b
  float* redC  = (float*)(uni + 8192);
  float* aw_l  = (float*)uni;                    // B1: [2][288] padded aw/aw_cum
  float* q_l   = (float*)(uni + 2304);           // B1: 16 f32
  u16*   im2   = (u16*)(uni + 2368);             // B1: 16384 B im2col A-frags
  float* e_l   = (float*)uni;                    // B2
  float* r_l   = (float*)(uni + 1024);
  float* awn_l = (float*)(uni + 1088);

  const int blk = blockIdx.x;
  const int tid = threadIdx.x;
  const int bb = blk & 31, rr = blk >> 5;        // batch / role within batch group
  const int w = tid >> 6, l = tid & 63;

  { // load persistent weights into LDS
    const uint4* s  = (const uint4*)(p.wfA + (size_t)blk*56*512);
    uint4* d = (uint4*)wA;
    for (int i2 = tid; i2 < 3584; i2 += NTHR) d[i2] = s[i2];
    const uint4* s2 = (const uint4*)(p.wfC + (size_t)blk*80*512);
    uint4* d2 = (uint4*)wC;
    for (int i2 = tid; i2 < 5120; i2 += NTHR) d2[i2] = s2[i2];
    if (tid < 16){
      int R = ((tid >> 2) << 10) + blk*4 + (tid & 3);
      bias_l[tid] = p.ab[R];
    } else if (tid < 32){
      int c = tid - 16;
      int R = ((c >> 2) << 10) + blk*4 + (c & 3);
      bias_l[tid] = p.db[R];
    }
  }
  __syncthreads();

  float att_c = 0.f, dec_c = 0.f;    // persistent cell states (tid<128 att, 128..255 dec)
  unsigned int ep = 0;

  for (int i = 0; i <= 400; ++i){
    const bool hasA = (i < 400), hasC = (i > 0);

    // ================= phase CA: A(i) on waves 0-3, C(i-1) on waves 4-7 =================
    if (hasA && w < 4){
      f32x4 acc0 = {0.f,0.f,0.f,0.f}, acc1 = {0.f,0.f,0.f,0.f};
      const u16* xd = p.Xdyn + (size_t)(i & 1)*48*2*512;
      const u16* xs = p.xfrag + (size_t)i*8*2*512;
      for (int c = w*14; c < w*14 + 14; ++c){
        short8 bfr = *(const short8*)(wA + (c*64 + l)*8);
        const u16* abase = (c < 8) ? (xs + (size_t)c*2*512) : (xd + (size_t)(c - 8)*2*512);
        short8 a0 = *(const short8*)(abase + l*8);
        short8 a1 = *(const short8*)(abase + 512 + l*8);
        acc0 = __builtin_amdgcn_mfma_f32_16x16x32_bf16(a0, bfr, acc0, 0, 0, 0);
        acc1 = __builtin_amdgcn_mfma_f32_16x16x32_bf16(a1, bfr, acc1, 0, 0, 0);
      }
      int cc = l & 15, rg = l >> 4;
      *(f32x4*)(redA + (((w*2 + 0)*16 + cc) << 4) + (rg << 2)) = acc0;
      *(f32x4*)(redA + (((w*2 + 1)*16 + cc) << 4) + (rg << 2)) = acc1;
    }
    if (hasC && w >= 4){
      f32x4 acc0 = {0.f,0.f,0.f,0.f}, acc1 = {0.f,0.f,0.f,0.f};
      const u16* yb = p.Yf + (size_t)((i + 1) & 1)*80*2*512;
      for (int c = (w - 4)*20; c < (w - 4)*20 + 20; ++c){
        short8 bfr = *(const short8*)(wC + (c*64 + l)*8);
        short8 a0 = *(const short8*)(yb + (size_t)c*2*512 + l*8);
        short8 a1 = *(const short8*)(yb + (size_t)c*2*512 + 512 + l*8);
        acc0 = __builtin_amdgcn_mfma_f32_16x16x32_bf16(a0, bfr, acc0, 0, 0, 0);
        acc1 = __builtin_amdgcn_mfma_f32_16x16x32_bf16(a1, bfr, acc1, 0, 0, 0);
      }
      int cc = l & 15, rg = l >> 4, w4 = w - 4;
      *(f32x4*)(redC + (((w4*2 + 0)*16 + cc) << 4) + (rg << 2)) = acc0;
      *(f32x4*)(redC + (((w4*2 + 1)*16 + cc) << 4) + (rg << 2)) = acc1;
    }
    __syncthreads();
    if (hasA && tid < 128){   // att LSTM state update for (b, d); this block owns dims blk*4+d
      int b = tid >> 2, d = tid & 3, mt = b >> 4, b15 = b & 15;
      float gi = bias_l[d], gf = bias_l[4 + d], gg = bias_l[8 + d], go = bias_l[12 + d];
      #pragma unroll
      for (int w2 = 0; w2 < 4; ++w2){
        const float* base = redA + (((w2*2 + mt)*16) << 4) + b15;
        gi += base[(d) << 4]; gf += base[(4 + d) << 4];
        gg += base[(8 + d) << 4]; go += base[(12 + d) << 4];
      }
      att_c = sigm(gf)*att_c + sigm(gi)*tanhf(gg);
      float h = sigm(go)*tanhf(att_c);
      int hidx = blk*4 + d;
      p.ah[b*1024 + hidx] = h;
      u16 hb = f2bf(h);
      { int k = hidx, ch = k >> 5, kk = k & 31;
        p.Yf[(size_t)(((i & 1)*80 + ch)*2 + mt)*512 + frag_off(b15, kk)] = hb; }
      { int k = 768 + hidx, ch = (k >> 5) - 8, kk = k & 31;
        p.Xdyn[(size_t)((((i + 1) & 1)*48 + ch)*2 + mt)*512 + frag_off(b15, kk)] = hb; }
    }
    if (hasC && tid >= 128 && tid < 256){   // dec LSTM state update (step i-1)
      int t2 = tid - 128;
      int b = t2 >> 2, d = t2 & 3, mt = b >> 4, b15 = b & 15;
      float gi = bias_l[16 + d], gf = bias_l[16 + 4 + d], gg = bias_l[16 + 8 + d], go = bias_l[16 + 12 + d];
      #pragma unroll
      for (int w2 = 0; w2 < 4; ++w2){
        const float* base = redC + (((w2*2 + mt)*16) << 4) + b15;
        gi += base[(d) << 4]; gf += base[(4 + d) << 4];
        gg += base[(8 + d) << 4]; go += base[(12 + d) << 4];
      }
      dec_c = sigm(gf)*dec_c + sigm(gi)*tanhf(gg);
      float h = sigm(go)*tanhf(dec_c);
      int hidx = blk*4 + d;
      p.dh[b*1024 + hidx] = h;
      u16 hb = f2bf(h);
      { int k = 1536 + hidx, ch = k >> 5, kk = k & 31;
        p.Yf[(size_t)(((i & 1)*80 + ch)*2 + mt)*512 + frag_off(b15, kk)] = hb; }
    }
    gbar(p.bar, ++ep);

    // ================= phase B1: q-slice + energies (+ projection of step i-1) ==========
    if (hasA){
      for (int s = tid; s < 576; s += NTHR){
        int c = s / 288, o = s - c*288;
        float v2 = 0.f;
        if (o >= 16 && o < 272) v2 = c ? p.awc[bb*256 + (o - 16)] : p.aw[bb*256 + (o - 16)];
        aw_l[s] = v2;
      }
      { // q slice for a in [rr*16, rr*16+16)
        int asub = tid >> 5, ksub = tid & 31;
        const float* qwr = p.qW + (size_t)(rr*16 + asub)*1024;
        const float* ahr = p.ah + bb*1024;
        float s = 0.f;
        for (int m = 0; m < 32; ++m){
          int k = ksub + (m << 5);
          s += qwr[k] * ahr[k];
        }
        s += __shfl_xor(s, 16, 32); s += __shfl_xor(s, 8, 32);
        s += __shfl_xor(s, 4, 32);  s += __shfl_xor(s, 2, 32); s += __shfl_xor(s, 1, 32);
        if (ksub == 0) q_l[asub] = s;
      }
      __syncthreads();
      #pragma unroll 1
      for (int hh = 0; hh < 2; ++hh){     // two t'-halves of 128
        for (int s = tid; s < 8192; s += NTHR){
          int jj = s & 7, ll = (s >> 3) & 63, kc = (s >> 9) & 1, mt = s >> 10;
          int trow = hh*128 + mt*16 + (ll & 15);
          int k = kc*32 + ((ll >> 4) << 3) + jj;
          float v2 = 0.f;
          if (k < 31) v2 = aw_l[1 + trow + k];
          else if (k >= 32 && k < 63) v2 = aw_l[289 + trow + (k - 32)];
          im2[s] = f2bf(v2);
        }
        __syncthreads();
        {
          f32x4 acc = {0.f,0.f,0.f,0.f};
          short8 a0 = *(const short8*)(im2 + ((w*2 + 0)*64 + l)*8);
          short8 b0 = *(const short8*)(p.ckf + (size_t)rr*1024 + (0*64 + l)*8);
          short8 a1 = *(const short8*)(im2 + ((w*2 + 1)*64 + l)*8);
          short8 b1 = *(const short8*)(p.ckf + (size_t)rr*1024 + (1*64 + l)*8);
          acc = __builtin_amdgcn_mfma_f32_16x16x32_bf16(a0, b0, acc, 0, 0, 0);
          acc = __builtin_amdgcn_mfma_f32_16x16x32_bf16(a1, b1, acc, 0, 0, 0);
          int a_l = l & 15, rg = l >> 4;
          float q_a = q_l[a_l];
          float va = p.vW[rr*16 + a_l];
          int tbase = hh*128 + w*16 + rg*4;
          const float* pmr = p.pmT + (size_t)(bb*128 + rr*16 + a_l)*256 + tbase;
          f32x4 pv = *(const f32x4*)pmr;
          float e0 = va * tanhf(acc[0] + q_a + pv[0]);
          float e1 = va * tanhf(acc[1] + q_a + pv[1]);
          float e2 = va * tanhf(acc[2] + q_a + pv[2]);
          float e3 = va * tanhf(acc[3] + q_a + pv[3]);
          #pragma unroll
          for (int msk = 8; msk >= 1; msk >>= 1){
            e0 += __shfl_xor(e0, msk, 16);
            e1 += __shfl_xor(e1, msk, 16);
            e2 += __shfl_xor(e2, msk, 16);
            e3 += __shfl_xor(e3, msk, 16);
          }
          if (a_l == 0){
            f32x4 evv = {e0, e1, e2, e3};
            *(f32x4*)(p.e_buf + (size_t)(bb*8 + rr)*256 + tbase) = evv;
          }
        }
        __syncthreads();
      }
    }
    if (hasC){   // projection for step i-1 (rows rr*10.., gate row = 80)
      int grp = tid >> 5, gl = tid & 31;
      int cnt = (rr == 7) ? 11 : 10;
      if (grp < cnt){
        int r = rr*10 + grp;
        const float* wrow = (r < 80) ? (p.pjW + (size_t)r*1536) : p.gW;
        const float* dhr = p.dh + bb*1024;
        const float* cxr = p.ctx + bb*512;
        float s = 0.f;
        for (int k = gl; k < 1024; k += 32) s += wrow[k] * dhr[k];
        for (int k = gl; k < 512;  k += 32) s += wrow[1024 + k] * cxr[k];
        s += __shfl_xor(s, 16, 32); s += __shfl_xor(s, 8, 32);
        s += __shfl_xor(s, 4, 32);  s += __shfl_xor(s, 2, 32); s += __shfl_xor(s, 1, 32);
        if (gl == 0){
          if (r < 80) p.out_mel[(size_t)(bb*80 + r)*400 + (i - 1)] = s + p.pjb[r];
          else        p.out_gate[bb*400 + (i - 1)] = s + p.gb[0];
        }
      }
    }
    if (i == 400) break;
    gbar(p.bar, ++ep);

    // ================= phase B2: softmax (redundant per rr) + ctx slice ==================
    {
      int len = p.lens[bb];
      if (tid < 256){
        float s = 0.f;
        #pragma unroll
        for (int r2 = 0; r2 < 8; ++r2) s += p.e_buf[(size_t)(bb*8 + r2)*256 + tid];
        if (tid >= len) s = -1e9f;
        e_l[tid] = s;
      }
      __syncthreads();
      float v2 = (tid < 256) ? e_l[tid] : -3.0e38f;
      #pragma unroll
      for (int off = 32; off >= 1; off >>= 1) v2 = fmaxf(v2, __shfl_xor(v2, off, 64));
      if ((tid & 63) == 0) r_l[tid >> 6] = v2;
      __syncthreads();
      if (tid == 0){
        float m2 = r_l[0];
        #pragma unroll
        for (int w2 = 1; w2 < 8; ++w2) m2 = fmaxf(m2, r_l[w2]);
        r_l[8] = m2;
      }
      __syncthreads();
      float mx = r_l[8];
      float exv = (tid < 256) ? expf(e_l[tid] - mx) : 0.f;
      float sv = exv;
      #pragma unroll
      for (int off = 32; off >= 1; off >>= 1) sv += __shfl_xor(sv, off, 64);
      if ((tid & 63) == 0) r_l[tid >> 6] = sv;
      __syncthreads();
      if (tid == 0){
        float ss = 0.f;
        #pragma unroll
        for (int w2 = 0; w2 < 8; ++w2) ss += r_l[w2];
        r_l[9] = 1.f / ss;
      }
      __syncthreads();
      float awn = exv * r_l[9];
      if (tid < 256){
        awn_l[tid] = awn;
        if (rr == 0){
          p.aw[bb*256 + tid] = awn;
          p.awc[bb*256 + tid] += awn;
          p.out_align[(size_t)(bb*400 + i)*256 + tid] = awn;
        }
      }
      __syncthreads();
      { // ctx slice e' in [rr*64, rr*64+64)
        int el = rr*64 + (tid >> 3), g = tid & 7;
        const float* mr = p.memory + (size_t)bb*256*512 + el;
        float s2 = 0.f;
        for (int t2 = g; t2 < 256; t2 += 8) s2 += awn_l[t2] * mr[(size_t)t2*512];
        s2 += __shfl_xor(s2, 4, 8); s2 += __shfl_xor(s2, 2, 8); s2 += __shfl_xor(s2, 1, 8);
        if (g == 0){
          p.ctx[bb*512 + el] = s2;
          u16 cb = f2bf(s2);
          int mt = bb >> 4, b15 = bb & 15;
          { int k = 1024 + el, ch = k >> 5, kk = k & 31;
            p.Yf[(size_t)(((i & 1)*80 + ch)*2 + mt)*512 + frag_off(b15, kk)] = cb; }
          { int k = 256 + el, ch = (k >> 5) - 8, kk = k & 31;
            p.Xdyn[(size_t)((((i + 1) & 1)*48 + ch)*2 + mt)*512 + frag_off(b15, kk)] = cb; }
        }
      }
    }
    gbar(p.bar, ++ep);
  }
}

// ---------------- host ----------------
extern "C" void kernel_launch(void* const* d_in, const int* in_sizes, int n_in,
                              void* d_out, int out_size, void* d_ws, size_t ws_size,
                              hipStream_t stream){
  (void)in_sizes; (void)n_in; (void)out_size; (void)ws_size;
  DP p;
  p.memory = (const float*)d_in[0];
  p.dec_in = (const float*)d_in[1];
  p.lens   = (const int*)d_in[2];
  p.pW1 = (const float*)d_in[3];  p.pW2 = (const float*)d_in[4];
  p.aWi = (const float*)d_in[5];  p.aWh = (const float*)d_in[6];  p.ab = (const float*)d_in[7];
  p.cW  = (const float*)d_in[8];  p.ldW = (const float*)d_in[9];  p.qW = (const float*)d_in[10];
  p.mW  = (const float*)d_in[11]; p.vW  = (const float*)d_in[12];
  p.dWi = (const float*)d_in[13]; p.dWh = (const float*)d_in[14]; p.db = (const float*)d_in[15];
  p.pjW = (const float*)d_in[16]; p.pjb = (const float*)d_in[17];
  p.gW  = (const float*)d_in[18]; p.gb  = (const float*)d_in[19];

  char* ws = (char*)d_ws;
  size_t o = 0;
  auto take = [&](size_t bytes)->char*{ char* r = ws + o; o += (bytes + 255) & ~(size_t)255; return r; };
  p.xfrag = (u16*)take((size_t)3276800*2);
  p.h1f   = (u16*)take((size_t)3276800*2);
  p.w2f   = (u16*)take((size_t)65536*2);
  p.wfA   = (u16*)take((size_t)7340032*2);
  p.wfC   = (u16*)take((size_t)10485760*2);
  p.ckf   = (u16*)take((size_t)8192*2);
  p.pmT   = (float*)take((size_t)1048576*4);
  p.e_buf = (float*)take((size_t)65536*4);
  p.ah    = (float*)take((size_t)32768*4);
  p.dh    = (float*)take((size_t)32768*4);
  p.ctx   = (float*)take((size_t)16384*4);
  char* z0 = ws + o;                     // zero-init region
  p.Xdyn  = (u16*)take((size_t)98304*2);
  p.Yf    = (u16*)take((size_t)163840*2);
  p.aw    = (float*)take((size_t)8192*4);
  p.awc   = (float*)take((size_t)8192*4);
  p.bar   = (unsigned int*)take(256*64);   // 256 epoch slots, 64B apart
  size_t zbytes = (size_t)((ws + o) - z0);

  float* out = (float*)d_out;
  p.out_mel   = out;
  p.out_gate  = out + 1024000;
  p.out_align = out + 1036800;

  hipMemsetAsync(z0, 0, zbytes, stream);
  // order matters: k_h2 consumes w2f (from k_wfrag) and h1f (from k_pre1)
  k_pre1 <<<dim3(12800), dim3(256), 0, stream>>>(p);
  k_wfrag<<<dim3(4368),  dim3(512), 0, stream>>>(p);
  k_ck   <<<dim3(16),    dim3(512), 0, stream>>>(p);
  k_pm   <<<dim3(256),   dim3(512), 0, stream>>>(p);
  k_h2   <<<dim3(800),   dim3(256), 0, stream>>>(p);

  hipFuncSetAttribute(reinterpret_cast<const void*>(k_decoder),
                      hipFuncAttributeMaxDynamicSharedMemorySize, LDS_BYTES);
  DP pp = p;
  void* args[] = { &pp };
  hipError_t err = hipLaunchCooperativeKernel(reinterpret_cast<void*>(k_decoder),
                                              dim3(NBLK), dim3(NTHR), args,
                                              (unsigned int)LDS_BYTES, stream);
  if (err != hipSuccess){
    // co-residency still guaranteed: 256 blocks, 158KB LDS -> exactly 1 block/CU on 256 CUs
    k_decoder<<<dim3(NBLK), dim3(NTHR), LDS_BYTES, stream>>>(pp);
  }
}

// Round 5
// 17493.108 us; speedup vs baseline: 2.7531x; 1.4268x over previous
//
#include <hip/hip_runtime.h>
#include <stdint.h>

typedef unsigned short u16;
typedef unsigned long long u64;
typedef __attribute__((ext_vector_type(8))) short short8;
typedef __attribute__((ext_vector_type(4))) float f32x4;

#define NBLK 256
#define NTHR 512
#define LDS_BYTES 158144

__device__ __forceinline__ float bf2f(u16 u){
  union { unsigned int i; float f; } v; v.i = ((unsigned int)u) << 16; return v.f;
}
__device__ __forceinline__ u16 f2bf(float f){
  union { float f; unsigned int i; } v; v.f = f;
  unsigned int u = v.i;
  u += 0x7fffu + ((u >> 16) & 1u);
  return (u16)(u >> 16);
}
__device__ __forceinline__ unsigned int pk2(float a, float b){
  return (unsigned int)f2bf(a) | ((unsigned int)f2bf(b) << 16);
}
__device__ __forceinline__ float sigm(float x){ return 1.f/(1.f + expf(-x)); }

// ---- coherent (agent-scope, L1/L2-bypassing) access helpers ----
__device__ __forceinline__ u64 coh_ld64(const void* p){
  return __hip_atomic_load((const u64*)p, __ATOMIC_RELAXED, __HIP_MEMORY_SCOPE_AGENT);
}
__device__ __forceinline__ float coh_ldf(const float* p){
  return __hip_atomic_load(p, __ATOMIC_RELAXED, __HIP_MEMORY_SCOPE_AGENT);
}
__device__ __forceinline__ unsigned int coh_ldu(const unsigned int* p){
  return __hip_atomic_load(p, __ATOMIC_RELAXED, __HIP_MEMORY_SCOPE_AGENT);
}
__device__ __forceinline__ void coh_stf(float* p, float v){
  __hip_atomic_store(p, v, __ATOMIC_RELAXED, __HIP_MEMORY_SCOPE_AGENT);
}
__device__ __forceinline__ void coh_stu(unsigned int* p, unsigned int v){
  __hip_atomic_store(p, v, __ATOMIC_RELAXED, __HIP_MEMORY_SCOPE_AGENT);
}
__device__ __forceinline__ void coh_st64(void* p, u64 v){
  __hip_atomic_store((u64*)p, v, __ATOMIC_RELAXED, __HIP_MEMORY_SCOPE_AGENT);
}

struct DP {
  const float *memory, *dec_in, *pW1, *pW2, *aWi, *aWh, *ab;
  const float *cW, *ldW, *qW, *mW, *vW, *dWi, *dWh, *db, *pjW, *pjb, *gW, *gb;
  const int* lens;
  u16 *xfrag, *h1f, *w2f, *wfA, *wfC, *ckf;
  float *pmT, *e_buf, *ah, *dh, *ctx;
  u16 *Xdyn, *Yf;
  float *aw, *awc;
  unsigned int* bar;     // 256 slots, 64B apart (u32 index stride 16)
  float *out_mel, *out_gate, *out_align;
};

// fragment indexing: within one (chunk,mtile) block of [64 lanes][8], element for
// (row m15, k-in-chunk kk) sits at lane=(m15 | ((kk>>3)<<4)), j=kk&7
__device__ __forceinline__ int frag_off(int m15, int kk){
  return ((m15) | ((kk >> 3) << 4)) * 8 + (kk & 7);
}

// batched coherent A-fragment load + MFMA over NB chunks (both m-tiles).
// Issues all 4*NB u64 loads before first use so only one LLC latency is paid.
template<int NB>
__device__ __forceinline__ void mfma_ab_batch(const u16* abase0, const u16* wlds, int c0, int l,
                                              f32x4& acc0, f32x4& acc1){
  u64 q0[NB], q1[NB], q2[NB], q3[NB];
  #pragma unroll
  for (int t = 0; t < NB; ++t){
    const u16* ab = abase0 + (size_t)(c0 + t)*1024 + l*8;
    q0[t] = coh_ld64(ab);
    q1[t] = coh_ld64(ab + 4);
    q2[t] = coh_ld64(ab + 512);
    q3[t] = coh_ld64(ab + 516);
  }
  #pragma unroll
  for (int t = 0; t < NB; ++t){
    short8 bfr = *(const short8*)(wlds + ((c0 + t)*64 + l)*8);
    union { u64 q[2]; short8 v; } a0, a1;
    a0.q[0] = q0[t]; a0.q[1] = q1[t];
    a1.q[0] = q2[t]; a1.q[1] = q3[t];
    acc0 = __builtin_amdgcn_mfma_f32_16x16x32_bf16(a0.v, bfr, acc0, 0, 0, 0);
    acc1 = __builtin_amdgcn_mfma_f32_16x16x32_bf16(a1.v, bfr, acc1, 0, 0, 0);
  }
}

// ---------------- prelude kernels ----------------

__global__ void k_pre1(DP p){
  int t = blockIdx.x >> 5, b = blockIdx.x & 31;
  int tid = threadIdx.x;
  __shared__ float fr[80];
  if (tid < 80) fr[tid] = (t == 0) ? 0.f : p.dec_in[(b*80 + tid)*400 + (t-1)];
  __syncthreads();
  const float* w = p.pW1 + (size_t)tid*80;
  float s = 0.f;
  #pragma unroll
  for (int m4 = 0; m4 < 20; ++m4){
    float4 wv = *(const float4*)(w + m4*4);
    s += wv.x*fr[m4*4] + wv.y*fr[m4*4+1] + wv.z*fr[m4*4+2] + wv.w*fr[m4*4+3];
  }
  s = fmaxf(s, 0.f);
  int row = blockIdx.x;            // = t*32 + b
  int rt = row >> 4, m15 = row & 15;
  int kc = tid >> 5, kk = tid & 31;
  p.h1f[(size_t)(rt*8 + kc)*512 + frag_off(m15, kk)] = f2bf(s);
}

__global__ void k_h2(DP p){
  int rt = blockIdx.x;
  int tid = threadIdx.x, w = tid >> 6, l = tid & 63;
  const u16* abase = p.h1f + (size_t)rt*8*512;
  short8 af[8];
  #pragma unroll
  for (int kc = 0; kc < 8; ++kc) af[kc] = *(const short8*)(abase + kc*512 + l*8);
  for (int nt = w; nt < 16; nt += 4){
    f32x4 acc = {0.f,0.f,0.f,0.f};
    #pragma unroll
    for (int kc = 0; kc < 8; ++kc){
      short8 bf = *(const short8*)(p.w2f + (size_t)((nt*8 + kc)*64 + l)*8);
      acc = __builtin_amdgcn_mfma_f32_16x16x32_bf16(af[kc], bf, acc, 0, 0, 0);
    }
    int ncol = l & 15, rg = l >> 4;
    #pragma unroll
    for (int r = 0; r < 4; ++r){
      float v = fmaxf(acc[r], 0.f);
      int row = rt*16 + rg*4 + r;
      int t = row >> 5, b = row & 31;
      int n = nt*16 + ncol;
      int ch = n >> 5, kk = n & 31, mt = b >> 4;
      p.xfrag[(size_t)((t*8 + ch)*2 + mt)*512 + frag_off(b & 15, kk)] = f2bf(v);
    }
  }
}

__global__ void k_pm(DP p){
  int b = blockIdx.x & 31, tt = blockIdx.x >> 5;
  int tid = threadIdx.x;
  __shared__ u16 ml[32*516];
  for (int s = tid; s < 32*512; s += 512){
    int r = s >> 9, e = s & 511;
    ml[r*516 + e] = f2bf(p.memory[(size_t)((b*256) + tt*32 + r)*512 + e]);
  }
  __syncthreads();
  int a = tid >> 2, tg = tid & 3;
  const float* wr = p.mW + (size_t)a*512;
  float acc[8];
  #pragma unroll
  for (int m = 0; m < 8; ++m) acc[m] = 0.f;
  for (int e8 = 0; e8 < 64; ++e8){
    float4 w0 = *(const float4*)(wr + e8*8);
    float4 w1 = *(const float4*)(wr + e8*8 + 4);
    float wf[8] = {w0.x,w0.y,w0.z,w0.w,w1.x,w1.y,w1.z,w1.w};
    #pragma unroll
    for (int q = 0; q < 8; ++q){
      int e = e8*8 + q;
      #pragma unroll
      for (int m = 0; m < 8; ++m) acc[m] += wf[q] * bf2f(ml[(tg*8 + m)*516 + e]);
    }
  }
  float* dst = p.pmT + (size_t)(b*128 + a)*256 + tt*32 + tg*8;
  f32x4 v0 = {acc[0],acc[1],acc[2],acc[3]}, v1 = {acc[4],acc[5],acc[6],acc[7]};
  *(f32x4*)dst = v0; *(f32x4*)(dst + 4) = v1;
}

__global__ void k_ck(DP p){
  int s = blockIdx.x*512 + threadIdx.x;   // 0..8191
  if (s >= 8192) return;
  int slice = s >> 10;
  int rem = s & 1023;
  int l = (rem >> 3) & 63, j = rem & 7, kc = rem >> 9;
  int a = slice*16 + (l & 15), k = kc*32 + ((l >> 4) << 3) + j;
  float val = 0.f;
  if (k != 31 && k != 63){
    int c = (k >= 32) ? 1 : 0, tap = k - (c ? 32 : 0);
    for (int f = 0; f < 32; ++f)
      val += p.ldW[a*32 + f] * p.cW[(f*2 + c)*31 + tap];
  }
  p.ckf[s] = f2bf(val);
}

__global__ void k_wfrag(DP p){
  int g = blockIdx.x*512 + threadIdx.x;
  const int GA = 256*56*64;        // 917504
  const int GC = 256*80*64;        // 1310720
  const float* src;
  u16* dst;
  if (g < GA){
    int j = g / (56*64); int rem = g - j*56*64; int ch = rem >> 6; int l = rem & 63;
    int c = l & 15, R = ((c >> 2) << 10) + j*4 + (c & 3);
    int k0 = ch*32 + ((l >> 4) << 3);
    src = (k0 < 768) ? (p.aWi + (size_t)R*768 + k0) : (p.aWh + (size_t)R*1024 + (k0 - 768));
    dst = p.wfA + (size_t)g*8;
  } else if (g < GA + GC){
    int g2 = g - GA;
    int j = g2 / (80*64); int rem = g2 - j*80*64; int ch = rem >> 6; int l = rem & 63;
    int c = l & 15, R = ((c >> 2) << 10) + j*4 + (c & 3);
    int k0 = ch*32 + ((l >> 4) << 3);
    src = (k0 < 1536) ? (p.dWi + (size_t)R*1536 + k0) : (p.dWh + (size_t)R*1024 + (k0 - 1536));
    dst = p.wfC + (size_t)g2*8;
  } else {
    int g3 = g - GA - GC;            // < 8192
    int nt = g3 >> 9; int rem = g3 & 511; int kc = rem >> 6; int l = rem & 63;
    src = p.pW2 + (size_t)(nt*16 + (l & 15))*256 + kc*32 + ((l >> 4) << 3);
    dst = p.w2f + (size_t)g3*8;
  }
  float4 v0 = *(const float4*)src;
  float4 v1 = *(const float4*)(src + 4);
  uint4 o;
  o.x = pk2(v0.x, v0.y); o.y = pk2(v0.z, v0.w);
  o.z = pk2(v1.x, v1.y); o.w = pk2(v1.z, v1.w);
  *(uint4*)dst = o;
}

// ---------------- grid barrier (all-poll, no cache invalidation) ----------------
// All cross-block data uses sc0/sc1 (LLC-coherent) accesses, so the barrier needs
// NO buffer_inv / buffer_wbl2. __syncthreads drains each wave's stores (vmcnt(0)
// before s_barrier); slot store + relaxed all-poll + compiler barrier suffice.
__device__ __forceinline__ void gbar(unsigned int* slots, unsigned int ep){
  __syncthreads();
  if (threadIdx.x == 0){
    coh_stu(&slots[blockIdx.x << 4], ep);
  }
  if (threadIdx.x < 64){
    const int base = threadIdx.x << 2;
    for (;;){
      unsigned int a = coh_ldu(&slots[(base + 0) << 4]);
      unsigned int b = coh_ldu(&slots[(base + 1) << 4]);
      unsigned int c = coh_ldu(&slots[(base + 2) << 4]);
      unsigned int d = coh_ldu(&slots[(base + 3) << 4]);
      bool ok = (a >= ep) & (b >= ep) & (c >= ep) & (d >= ep);
      if (__all(ok)) break;
    }
  }
  asm volatile("" ::: "memory");
  __syncthreads();
}

// ---------------- persistent decoder ----------------
__launch_bounds__(NTHR, 2)
__global__ void k_decoder(DP p){
  extern __shared__ char smem[];
  u16*   wA     = (u16*)smem;                    // 57344 B: att weight frags (16 cols)
  u16*   wC     = (u16*)(smem + 57344);          // 81920 B: dec weight frags
  float* bias_l = (float*)(smem + 139264);       // 32 f32
  char*  uni    = smem + 139392;                 // 18752 B phase-union
  float* redA  = (float*)uni;                    // CA: 4 waves x 2mt x 16c x 16b
  float* redC  = (float*)(uni + 8192);
  float* aw_l  = (float*)uni;                    // B1: [2][288] padded aw/aw_cum
  float* q_l   = (float*)(uni + 2304);           // B1: 16 f32
  u16*   im2   = (u16*)(uni + 2368);             // B1: 16384 B im2col / f32 staging
  float* e_l   = (float*)uni;                    // B2
  float* r_l   = (float*)(uni + 1024);
  float* awn_l = (float*)(uni + 1088);

  const int blk = blockIdx.x;
  const int tid = threadIdx.x;
  const int bb = blk & 31, rr = blk >> 5;        // batch / role within batch group
  const int w = tid >> 6, l = tid & 63;

  { // load persistent weights into LDS (read-only global: plain cached loads)
    const uint4* s  = (const uint4*)(p.wfA + (size_t)blk*56*512);
    uint4* d = (uint4*)wA;
    for (int i2 = tid; i2 < 3584; i2 += NTHR) d[i2] = s[i2];
    const uint4* s2 = (const uint4*)(p.wfC + (size_t)blk*80*512);
    uint4* d2 = (uint4*)wC;
    for (int i2 = tid; i2 < 5120; i2 += NTHR) d2[i2] = s2[i2];
    if (tid < 16){
      int R = ((tid >> 2) << 10) + blk*4 + (tid & 3);
      bias_l[tid] = p.ab[R];
    } else if (tid < 32){
      int c = tid - 16;
      int R = ((c >> 2) << 10) + blk*4 + (c & 3);
      bias_l[tid] = p.db[R];
    }
  }
  __syncthreads();

  float att_c = 0.f, dec_c = 0.f;    // persistent cell states (tid<128 att, 128..255 dec)
  unsigned int ep = 0;

  for (int i = 0; i <= 400; ++i){
    const bool hasA = (i < 400), hasC = (i > 0);

    // ================= phase CA: A(i) on waves 0-3, C(i-1) on waves 4-7 =================
    if (hasA && w < 4){
      f32x4 acc0 = {0.f,0.f,0.f,0.f}, acc1 = {0.f,0.f,0.f,0.f};
      const u16* xd = p.Xdyn + (size_t)(i & 1)*57344;   // all 56 chunks coherent
      int c0 = w*14;
      mfma_ab_batch<7>(xd, wA, c0,     l, acc0, acc1);
      mfma_ab_batch<7>(xd, wA, c0 + 7, l, acc0, acc1);
      int cc = l & 15, rg = l >> 4;
      *(f32x4*)(redA + (((w*2 + 0)*16 + cc) << 4) + (rg << 2)) = acc0;
      *(f32x4*)(redA + (((w*2 + 1)*16 + cc) << 4) + (rg << 2)) = acc1;
    }
    if (hasC && w >= 4){
      f32x4 acc0 = {0.f,0.f,0.f,0.f}, acc1 = {0.f,0.f,0.f,0.f};
      const u16* yb = p.Yf + (size_t)((i + 1) & 1)*81920;
      int c0 = (w - 4)*20;
      mfma_ab_batch<7>(yb, wC, c0,      l, acc0, acc1);
      mfma_ab_batch<7>(yb, wC, c0 + 7,  l, acc0, acc1);
      mfma_ab_batch<6>(yb, wC, c0 + 14, l, acc0, acc1);
      int cc = l & 15, rg = l >> 4, w4 = w - 4;
      *(f32x4*)(redC + (((w4*2 + 0)*16 + cc) << 4) + (rg << 2)) = acc0;
      *(f32x4*)(redC + (((w4*2 + 1)*16 + cc) << 4) + (rg << 2)) = acc1;
    }
    __syncthreads();
    if (hasA && tid < 128){   // att LSTM state update; this block owns dims blk*4+d
      int b = tid >> 2, d = tid & 3, mt = b >> 4, b15 = b & 15;
      float gi = bias_l[d], gf = bias_l[4 + d], gg = bias_l[8 + d], go = bias_l[12 + d];
      #pragma unroll
      for (int w2 = 0; w2 < 4; ++w2){
        const float* base = redA + (((w2*2 + mt)*16) << 4) + b15;
        gi += base[(d) << 4]; gf += base[(4 + d) << 4];
        gg += base[(8 + d) << 4]; go += base[(12 + d) << 4];
      }
      att_c = sigm(gf)*att_c + sigm(gi)*tanhf(gg);
      float h = sigm(go)*tanhf(att_c);
      int hidx = blk*4 + d;
      coh_stf(&p.ah[b*1024 + hidx], h);
      unsigned int hv = (unsigned int)f2bf(h);
      unsigned int ov = __shfl_xor(hv, 1, 64);
      if ((d & 1) == 0){
        unsigned int pk = hv | (ov << 16);
        { int k = hidx; int ch = k >> 5, kk = k & 31;
          coh_stu((unsigned int*)&p.Yf[(size_t)(((i & 1)*80 + ch)*2 + mt)*512 + frag_off(b15, kk)], pk); }
        { int k = 768 + hidx; int ch = k >> 5, kk = k & 31;
          coh_stu((unsigned int*)&p.Xdyn[(size_t)((((i + 1) & 1)*56 + ch)*2 + mt)*512 + frag_off(b15, kk)], pk); }
      }
    }
    if (hasC && tid >= 128 && tid < 256){   // dec LSTM state update (step i-1)
      int t2 = tid - 128;
      int b = t2 >> 2, d = t2 & 3, mt = b >> 4, b15 = b & 15;
      float gi = bias_l[16 + d], gf = bias_l[16 + 4 + d], gg = bias_l[16 + 8 + d], go = bias_l[16 + 12 + d];
      #pragma unroll
      for (int w2 = 0; w2 < 4; ++w2){
        const float* base = redC + (((w2*2 + mt)*16) << 4) + b15;
        gi += base[(d) << 4]; gf += base[(4 + d) << 4];
        gg += base[(8 + d) << 4]; go += base[(12 + d) << 4];
      }
      dec_c = sigm(gf)*dec_c + sigm(gi)*tanhf(gg);
      float h = sigm(go)*tanhf(dec_c);
      int hidx = blk*4 + d;
      coh_stf(&p.dh[b*1024 + hidx], h);
      unsigned int hv = (unsigned int)f2bf(h);
      unsigned int ov = __shfl_xor(hv, 1, 64);
      if ((d & 1) == 0){
        unsigned int pk = hv | (ov << 16);
        int k = 1536 + hidx; int ch = k >> 5, kk = k & 31;
        coh_stu((unsigned int*)&p.Yf[(size_t)(((i & 1)*80 + ch)*2 + mt)*512 + frag_off(b15, kk)], pk);
      }
    }
    gbar(p.bar, ++ep);

    // ================= phase B1: q-slice + energies (+ projection of step i-1) ==========
    if (hasA){
      float* sh_f = (float*)im2;          // stage ah[bb] (1024 f32) in im2 region
      for (int s = tid; s < 576; s += NTHR){
        int c = s / 288, o = s - c*288;
        float v2 = 0.f;
        if (o >= 16 && o < 272)
          v2 = c ? coh_ldf(&p.awc[bb*256 + (o - 16)]) : coh_ldf(&p.aw[bb*256 + (o - 16)]);
        aw_l[s] = v2;
      }
      sh_f[tid]       = coh_ldf(&p.ah[bb*1024 + tid]);
      sh_f[512 + tid] = coh_ldf(&p.ah[bb*1024 + 512 + tid]);
      __syncthreads();
      { // q slice for a in [rr*16, rr*16+16)
        int asub = tid >> 5, ksub = tid & 31;
        const float* qwr = p.qW + (size_t)(rr*16 + asub)*1024;
        float s = 0.f;
        for (int m = 0; m < 32; ++m){
          int k = ksub + (m << 5);
          s += qwr[k] * sh_f[k];
        }
        s += __shfl_xor(s, 16, 32); s += __shfl_xor(s, 8, 32);
        s += __shfl_xor(s, 4, 32);  s += __shfl_xor(s, 2, 32); s += __shfl_xor(s, 1, 32);
        if (ksub == 0) q_l[asub] = s;
      }
      __syncthreads();
      #pragma unroll 1
      for (int hh = 0; hh < 2; ++hh){     // two t'-halves of 128
        for (int s = tid; s < 8192; s += NTHR){
          int jj = s & 7, ll = (s >> 3) & 63, kc = (s >> 9) & 1, mt = s >> 10;
          int trow = hh*128 + mt*16 + (ll & 15);
          int k = kc*32 + ((ll >> 4) << 3) + jj;
          float v2 = 0.f;
          if (k < 31) v2 = aw_l[1 + trow + k];
          else if (k >= 32 && k < 63) v2 = aw_l[289 + trow + (k - 32)];
          im2[s] = f2bf(v2);
        }
        __syncthreads();
        {
          f32x4 acc = {0.f,0.f,0.f,0.f};
          short8 a0 = *(const short8*)(im2 + ((w*2 + 0)*64 + l)*8);
          short8 b0 = *(const short8*)(p.ckf + (size_t)rr*1024 + (0*64 + l)*8);
          short8 a1 = *(const short8*)(im2 + ((w*2 + 1)*64 + l)*8);
          short8 b1 = *(const short8*)(p.ckf + (size_t)rr*1024 + (1*64 + l)*8);
          acc = __builtin_amdgcn_mfma_f32_16x16x32_bf16(a0, b0, acc, 0, 0, 0);
          acc = __builtin_amdgcn_mfma_f32_16x16x32_bf16(a1, b1, acc, 0, 0, 0);
          int a_l = l & 15, rg = l >> 4;
          float q_a = q_l[a_l];
          float va = p.vW[rr*16 + a_l];
          int tbase = hh*128 + w*16 + rg*4;
          const float* pmr = p.pmT + (size_t)(bb*128 + rr*16 + a_l)*256 + tbase;
          f32x4 pv = *(const f32x4*)pmr;
          float e0 = va * tanhf(acc[0] + q_a + pv[0]);
          float e1 = va * tanhf(acc[1] + q_a + pv[1]);
          float e2 = va * tanhf(acc[2] + q_a + pv[2]);
          float e3 = va * tanhf(acc[3] + q_a + pv[3]);
          #pragma unroll
          for (int msk = 8; msk >= 1; msk >>= 1){
            e0 += __shfl_xor(e0, msk, 16);
            e1 += __shfl_xor(e1, msk, 16);
            e2 += __shfl_xor(e2, msk, 16);
            e3 += __shfl_xor(e3, msk, 16);
          }
          if (a_l == 0){
            union { float f[4]; u64 q[2]; } evv;
            evv.f[0]=e0; evv.f[1]=e1; evv.f[2]=e2; evv.f[3]=e3;
            u64* dst = (u64*)(p.e_buf + (size_t)(bb*8 + rr)*256 + tbase);
            coh_st64(&dst[0], evv.q[0]);
            coh_st64(&dst[1], evv.q[1]);
          }
        }
        __syncthreads();
      }
    }
    if (hasC){   // projection for step i-1 (rows rr*10.., gate row = 80)
      float* sh_f = (float*)im2;          // stage dh (1024) + ctx (512) of batch bb
      for (int s = tid; s < 1536; s += NTHR){
        float v = (s < 1024) ? coh_ldf(&p.dh[bb*1024 + s])
                             : coh_ldf(&p.ctx[bb*512 + (s - 1024)]);
        sh_f[s] = v;
      }
      __syncthreads();
      int grp = tid >> 5, gl = tid & 31;
      int cnt = (rr == 7) ? 11 : 10;
      if (grp < cnt){
        int r = rr*10 + grp;
        const float* wrow = (r < 80) ? (p.pjW + (size_t)r*1536) : p.gW;
        float s = 0.f;
        for (int k = gl; k < 1536; k += 32) s += wrow[k] * sh_f[k];
        s += __shfl_xor(s, 16, 32); s += __shfl_xor(s, 8, 32);
        s += __shfl_xor(s, 4, 32);  s += __shfl_xor(s, 2, 32); s += __shfl_xor(s, 1, 32);
        if (gl == 0){
          if (r < 80) p.out_mel[(size_t)(bb*80 + r)*400 + (i - 1)] = s + p.pjb[r];
          else        p.out_gate[bb*400 + (i - 1)] = s + p.gb[0];
        }
      }
    }
    if (i == 400) break;
    gbar(p.bar, ++ep);

    // ================= phase B2: softmax (redundant per rr) + ctx slice ==================
    {
      int len = p.lens[bb];
      if (tid < 256){
        float av[8];
        #pragma unroll
        for (int r2 = 0; r2 < 8; ++r2)
          av[r2] = coh_ldf(&p.e_buf[(size_t)(bb*8 + r2)*256 + tid]);
        float s = ((av[0]+av[1])+(av[2]+av[3])) + ((av[4]+av[5])+(av[6]+av[7]));
        if (tid >= len) s = -1e9f;
        e_l[tid] = s;
      }
      // copy next step's static-x fragments into Xdyn (8 blocks, 1 u32 each thread)
      if (rr == 1 && bb < 8 && i < 399){
        int idx = (bb << 9) | tid;      // 0..4095 u32
        unsigned int val = ((const unsigned int*)(p.xfrag + (size_t)(i + 1)*8192))[idx];
        coh_stu((unsigned int*)(p.Xdyn + (size_t)((i + 1) & 1)*57344) + idx, val);
      }
      __syncthreads();
      float v2 = (tid < 256) ? e_l[tid] : -3.0e38f;
      #pragma unroll
      for (int off = 32; off >= 1; off >>= 1) v2 = fmaxf(v2, __shfl_xor(v2, off, 64));
      if ((tid & 63) == 0) r_l[tid >> 6] = v2;
      __syncthreads();
      if (tid == 0){
        float m2 = r_l[0];
        #pragma unroll
        for (int w2 = 1; w2 < 8; ++w2) m2 = fmaxf(m2, r_l[w2]);
        r_l[8] = m2;
      }
      __syncthreads();
      float mx = r_l[8];
      float exv = (tid < 256) ? expf(e_l[tid] - mx) : 0.f;
      float sv = exv;
      #pragma unroll
      for (int off = 32; off >= 1; off >>= 1) sv += __shfl_xor(sv, off, 64);
      if ((tid & 63) == 0) r_l[tid >> 6] = sv;
      __syncthreads();
      if (tid == 0){
        float ss = 0.f;
        #pragma unroll
        for (int w2 = 0; w2 < 8; ++w2) ss += r_l[w2];
        r_l[9] = 1.f / ss;
      }
      __syncthreads();
      float awn = exv * r_l[9];
      if (tid < 256){
        awn_l[tid] = awn;
        if (rr == 0){
          coh_stf(&p.aw[bb*256 + tid], awn);
          float c0 = coh_ldf(&p.awc[bb*256 + tid]);
          coh_stf(&p.awc[bb*256 + tid], c0 + awn);
          p.out_align[(size_t)(bb*400 + i)*256 + tid] = awn;
        }
      }
      __syncthreads();
      { // ctx slice e' in [rr*64, rr*64+64)
        int el = rr*64 + (tid >> 3), g = tid & 7;
        const float* mr = p.memory + (size_t)bb*256*512 + el;   // read-only: cached
        float s2 = 0.f;
        for (int t2 = g; t2 < 256; t2 += 8) s2 += awn_l[t2] * mr[(size_t)t2*512];
        s2 += __shfl_xor(s2, 4, 8); s2 += __shfl_xor(s2, 2, 8); s2 += __shfl_xor(s2, 1, 8);
        if (g == 0){
          coh_stf(&p.ctx[bb*512 + el], s2);
          unsigned int cv = (unsigned int)f2bf(s2);
          unsigned int ov = __shfl_xor(cv, 8, 64);
          if (((tid >> 3) & 1) == 0){
            unsigned int pk = cv | (ov << 16);
            int mt = bb >> 4, b15 = bb & 15;
            { int k = 1024 + el; int ch = k >> 5, kk = k & 31;
              coh_stu((unsigned int*)&p.Yf[(size_t)(((i & 1)*80 + ch)*2 + mt)*512 + frag_off(b15, kk)], pk); }
            { int k = 256 + el; int ch = k >> 5, kk = k & 31;
              coh_stu((unsigned int*)&p.Xdyn[(size_t)((((i + 1) & 1)*56 + ch)*2 + mt)*512 + frag_off(b15, kk)], pk); }
          }
        }
      }
    }
    gbar(p.bar, ++ep);
  }
}

// ---------------- host ----------------
extern "C" void kernel_launch(void* const* d_in, const int* in_sizes, int n_in,
                              void* d_out, int out_size, void* d_ws, size_t ws_size,
                              hipStream_t stream){
  (void)in_sizes; (void)n_in; (void)out_size; (void)ws_size;
  DP p;
  p.memory = (const float*)d_in[0];
  p.dec_in = (const float*)d_in[1];
  p.lens   = (const int*)d_in[2];
  p.pW1 = (const float*)d_in[3];  p.pW2 = (const float*)d_in[4];
  p.aWi = (const float*)d_in[5];  p.aWh = (const float*)d_in[6];  p.ab = (const float*)d_in[7];
  p.cW  = (const float*)d_in[8];  p.ldW = (const float*)d_in[9];  p.qW = (const float*)d_in[10];
  p.mW  = (const float*)d_in[11]; p.vW  = (const float*)d_in[12];
  p.dWi = (const float*)d_in[13]; p.dWh = (const float*)d_in[14]; p.db = (const float*)d_in[15];
  p.pjW = (const float*)d_in[16]; p.pjb = (const float*)d_in[17];
  p.gW  = (const float*)d_in[18]; p.gb  = (const float*)d_in[19];

  char* ws = (char*)d_ws;
  size_t o = 0;
  auto take = [&](size_t bytes)->char*{ char* r = ws + o; o += (bytes + 255) & ~(size_t)255; return r; };
  p.xfrag = (u16*)take((size_t)3276800*2);
  p.h1f   = (u16*)take((size_t)3276800*2);
  p.w2f   = (u16*)take((size_t)65536*2);
  p.wfA   = (u16*)take((size_t)7340032*2);
  p.wfC   = (u16*)take((size_t)10485760*2);
  p.ckf   = (u16*)take((size_t)8192*2);
  p.pmT   = (float*)take((size_t)1048576*4);
  p.e_buf = (float*)take((size_t)65536*4);
  p.ah    = (float*)take((size_t)32768*4);
  p.dh    = (float*)take((size_t)32768*4);
  p.ctx   = (float*)take((size_t)16384*4);
  char* z0 = ws + o;                     // zero-init region
  p.Xdyn  = (u16*)take((size_t)114688*2);  // 2 x 56 chunks x 2 mt x 512
  p.Yf    = (u16*)take((size_t)163840*2);
  p.aw    = (float*)take((size_t)8192*4);
  p.awc   = (float*)take((size_t)8192*4);
  p.bar   = (unsigned int*)take(256*64);   // 256 epoch slots, 64B apart
  size_t zbytes = (size_t)((ws + o) - z0);

  float* out = (float*)d_out;
  p.out_mel   = out;
  p.out_gate  = out + 1024000;
  p.out_align = out + 1036800;

  hipMemsetAsync(z0, 0, zbytes, stream);
  // order matters: k_h2 consumes w2f (from k_wfrag) and h1f (from k_pre1)
  k_pre1 <<<dim3(12800), dim3(256), 0, stream>>>(p);
  k_wfrag<<<dim3(4368),  dim3(512), 0, stream>>>(p);
  k_ck   <<<dim3(16),    dim3(512), 0, stream>>>(p);
  k_pm   <<<dim3(256),   dim3(512), 0, stream>>>(p);
  k_h2   <<<dim3(800),   dim3(256), 0, stream>>>(p);
  // note: Xdyn[0] static-x chunks rely on x(t=0)==0 (go-frame is zeros, prenet has
  // no bias), so the memset above is the correct step-0 initialization.

  hipFuncSetAttribute(reinterpret_cast<const void*>(k_decoder),
                      hipFuncAttributeMaxDynamicSharedMemorySize, LDS_BYTES);
  DP pp = p;
  void* args[] = { &pp };
  hipError_t err = hipLaunchCooperativeKernel(reinterpret_cast<void*>(k_decoder),
                                              dim3(NBLK), dim3(NTHR), args,
                                              (unsigned int)LDS_BYTES, stream);
  if (err != hipSuccess){
    // co-residency still guaranteed: 256 blocks, 158KB LDS -> exactly 1 block/CU on 256 CUs
    k_decoder<<<dim3(NBLK), dim3(NTHR), LDS_BYTES, stream>>>(pp);
  }
}

// Round 6
// 15928.307 us; speedup vs baseline: 3.0236x; 1.0982x over previous
//
#include <hip/hip_runtime.h>
#include <stdint.h>

typedef unsigned short u16;
typedef unsigned long long u64;
typedef __attribute__((ext_vector_type(8))) short short8;
typedef __attribute__((ext_vector_type(4))) float f32x4;

#define NBLK 256
#define NTHR 512
#define LDS_BYTES 162240

__device__ __forceinline__ float bf2f(u16 u){
  union { unsigned int i; float f; } v; v.i = ((unsigned int)u) << 16; return v.f;
}
__device__ __forceinline__ u16 f2bf(float f){
  union { float f; unsigned int i; } v; v.f = f;
  unsigned int u = v.i;
  u += 0x7fffu + ((u >> 16) & 1u);
  return (u16)(u >> 16);
}
__device__ __forceinline__ unsigned int pk2(float a, float b){
  return (unsigned int)f2bf(a) | ((unsigned int)f2bf(b) << 16);
}
// fast transcendentals (rel err ~1e-6, below bf16 state rounding)
__device__ __forceinline__ float fsigm(float x){
  return __fdividef(1.f, 1.f + __expf(-x));
}
__device__ __forceinline__ float ftanh(float x){
  float ax = fabsf(x);
  float t = __expf(-2.f*ax);
  float r = __fdividef(1.f - t, 1.f + t);
  return copysignf(r, x);
}

// ---- coherent (agent-scope, LLC) access helpers ----
__device__ __forceinline__ u64 coh_ld64(const void* p){
  return __hip_atomic_load((const u64*)p, __ATOMIC_RELAXED, __HIP_MEMORY_SCOPE_AGENT);
}
__device__ __forceinline__ float coh_ldf(const float* p){
  return __hip_atomic_load(p, __ATOMIC_RELAXED, __HIP_MEMORY_SCOPE_AGENT);
}
__device__ __forceinline__ unsigned int coh_ldu(const unsigned int* p){
  return __hip_atomic_load(p, __ATOMIC_RELAXED, __HIP_MEMORY_SCOPE_AGENT);
}
__device__ __forceinline__ void coh_stf(float* p, float v){
  __hip_atomic_store(p, v, __ATOMIC_RELAXED, __HIP_MEMORY_SCOPE_AGENT);
}
__device__ __forceinline__ void coh_stu(unsigned int* p, unsigned int v){
  __hip_atomic_store(p, v, __ATOMIC_RELAXED, __HIP_MEMORY_SCOPE_AGENT);
}
__device__ __forceinline__ void coh_st64(void* p, u64 v){
  __hip_atomic_store((u64*)p, v, __ATOMIC_RELAXED, __HIP_MEMORY_SCOPE_AGENT);
}

struct DP {
  const float *memory, *dec_in, *pW1, *pW2, *aWi, *aWh, *ab;
  const float *cW, *ldW, *qW, *mW, *vW, *dWi, *dWh, *db, *pjW, *pjb, *gW, *gb;
  const int* lens;
  u16 *xfrag, *h1f, *w2f, *wfA, *wfC, *ckf;
  float *pmT, *e_buf, *ah, *dh, *ctx;
  u16 *Xdyn, *Yf;
  float *aw, *awc;
  unsigned int* bar;     // 256 slots, 64B apart
  float *out_mel, *out_gate, *out_align;
};

__device__ __forceinline__ int frag_off(int m15, int kk){
  return ((m15) | ((kk >> 3) << 4)) * 8 + (kk & 7);
}

// batched coherent A-fragment load + MFMA over NB chunks (both m-tiles).
template<int NB>
__device__ __forceinline__ void gemm_batch(const u16* abase, const u16* wlds, int c0, int l,
                                           f32x4& acc0, f32x4& acc1){
  u64 q0[NB], q1[NB], q2[NB], q3[NB];
  #pragma unroll
  for (int t = 0; t < NB; ++t){
    const u16* ab = abase + (size_t)(c0 + t)*1024 + l*8;
    q0[t] = coh_ld64(ab);
    q1[t] = coh_ld64(ab + 4);
    q2[t] = coh_ld64(ab + 512);
    q3[t] = coh_ld64(ab + 516);
  }
  #pragma unroll
  for (int t = 0; t < NB; ++t){
    short8 bfr = *(const short8*)(wlds + ((c0 + t)*64 + l)*8);
    union { u64 q[2]; short8 v; } a0, a1;
    a0.q[0] = q0[t]; a0.q[1] = q1[t];
    a1.q[0] = q2[t]; a1.q[1] = q3[t];
    acc0 = __builtin_amdgcn_mfma_f32_16x16x32_bf16(a0.v, bfr, acc0, 0, 0, 0);
    acc1 = __builtin_amdgcn_mfma_f32_16x16x32_bf16(a1.v, bfr, acc1, 0, 0, 0);
  }
}

// ---------------- prelude kernels ----------------

__global__ void k_pre1(DP p){
  int t = blockIdx.x >> 5, b = blockIdx.x & 31;
  int tid = threadIdx.x;
  __shared__ float fr[80];
  if (tid < 80) fr[tid] = (t == 0) ? 0.f : p.dec_in[(b*80 + tid)*400 + (t-1)];
  __syncthreads();
  const float* w = p.pW1 + (size_t)tid*80;
  float s = 0.f;
  #pragma unroll
  for (int m4 = 0; m4 < 20; ++m4){
    float4 wv = *(const float4*)(w + m4*4);
    s += wv.x*fr[m4*4] + wv.y*fr[m4*4+1] + wv.z*fr[m4*4+2] + wv.w*fr[m4*4+3];
  }
  s = fmaxf(s, 0.f);
  int row = blockIdx.x;
  int rt = row >> 4, m15 = row & 15;
  int kc = tid >> 5, kk = tid & 31;
  p.h1f[(size_t)(rt*8 + kc)*512 + frag_off(m15, kk)] = f2bf(s);
}

__global__ void k_h2(DP p){
  int rt = blockIdx.x;
  int tid = threadIdx.x, w = tid >> 6, l = tid & 63;
  const u16* abase = p.h1f + (size_t)rt*8*512;
  short8 af[8];
  #pragma unroll
  for (int kc = 0; kc < 8; ++kc) af[kc] = *(const short8*)(abase + kc*512 + l*8);
  for (int nt = w; nt < 16; nt += 4){
    f32x4 acc = {0.f,0.f,0.f,0.f};
    #pragma unroll
    for (int kc = 0; kc < 8; ++kc){
      short8 bf = *(const short8*)(p.w2f + (size_t)((nt*8 + kc)*64 + l)*8);
      acc = __builtin_amdgcn_mfma_f32_16x16x32_bf16(af[kc], bf, acc, 0, 0, 0);
    }
    int ncol = l & 15, rg = l >> 4;
    #pragma unroll
    for (int r = 0; r < 4; ++r){
      float v = fmaxf(acc[r], 0.f);
      int row = rt*16 + rg*4 + r;
      int t = row >> 5, b = row & 31;
      int n = nt*16 + ncol;
      int ch = n >> 5, kk = n & 31, mt = b >> 4;
      p.xfrag[(size_t)((t*8 + ch)*2 + mt)*512 + frag_off(b & 15, kk)] = f2bf(v);
    }
  }
}

__global__ void k_pm(DP p){
  int b = blockIdx.x & 31, tt = blockIdx.x >> 5;
  int tid = threadIdx.x;
  __shared__ u16 ml[32*516];
  for (int s = tid; s < 32*512; s += 512){
    int r = s >> 9, e = s & 511;
    ml[r*516 + e] = f2bf(p.memory[(size_t)((b*256) + tt*32 + r)*512 + e]);
  }
  __syncthreads();
  int a = tid >> 2, tg = tid & 3;
  const float* wr = p.mW + (size_t)a*512;
  float acc[8];
  #pragma unroll
  for (int m = 0; m < 8; ++m) acc[m] = 0.f;
  for (int e8 = 0; e8 < 64; ++e8){
    float4 w0 = *(const float4*)(wr + e8*8);
    float4 w1 = *(const float4*)(wr + e8*8 + 4);
    float wf[8] = {w0.x,w0.y,w0.z,w0.w,w1.x,w1.y,w1.z,w1.w};
    #pragma unroll
    for (int q = 0; q < 8; ++q){
      int e = e8*8 + q;
      #pragma unroll
      for (int m = 0; m < 8; ++m) acc[m] += wf[q] * bf2f(ml[(tg*8 + m)*516 + e]);
    }
  }
  float* dst = p.pmT + (size_t)(b*128 + a)*256 + tt*32 + tg*8;
  f32x4 v0 = {acc[0],acc[1],acc[2],acc[3]}, v1 = {acc[4],acc[5],acc[6],acc[7]};
  *(f32x4*)dst = v0; *(f32x4*)(dst + 4) = v1;
}

__global__ void k_ck(DP p){
  int s = blockIdx.x*512 + threadIdx.x;   // 0..8191
  if (s >= 8192) return;
  int slice = s >> 10;
  int rem = s & 1023;
  int l = (rem >> 3) & 63, j = rem & 7, kc = rem >> 9;
  int a = slice*16 + (l & 15), k = kc*32 + ((l >> 4) << 3) + j;
  float val = 0.f;
  if (k != 31 && k != 63){
    int c = (k >= 32) ? 1 : 0, tap = k - (c ? 32 : 0);
    for (int f = 0; f < 32; ++f)
      val += p.ldW[a*32 + f] * p.cW[(f*2 + c)*31 + tap];
  }
  p.ckf[s] = f2bf(val);
}

__global__ void k_wfrag(DP p){
  int g = blockIdx.x*512 + threadIdx.x;
  const int GA = 256*56*64;        // 917504
  const int GC = 256*80*64;        // 1310720
  const float* src;
  u16* dst;
  if (g < GA){
    int j = g / (56*64); int rem = g - j*56*64; int ch = rem >> 6; int l = rem & 63;
    int c = l & 15, R = ((c >> 2) << 10) + j*4 + (c & 3);
    int k0 = ch*32 + ((l >> 4) << 3);
    src = (k0 < 768) ? (p.aWi + (size_t)R*768 + k0) : (p.aWh + (size_t)R*1024 + (k0 - 768));
    dst = p.wfA + (size_t)g*8;
  } else if (g < GA + GC){
    int g2 = g - GA;
    int j = g2 / (80*64); int rem = g2 - j*80*64; int ch = rem >> 6; int l = rem & 63;
    int c = l & 15, R = ((c >> 2) << 10) + j*4 + (c & 3);
    int k0 = ch*32 + ((l >> 4) << 3);
    src = (k0 < 1536) ? (p.dWi + (size_t)R*1536 + k0) : (p.dWh + (size_t)R*1024 + (k0 - 1536));
    dst = p.wfC + (size_t)g2*8;
  } else {
    int g3 = g - GA - GC;            // < 8192
    int nt = g3 >> 9; int rem = g3 & 511; int kc = rem >> 6; int l = rem & 63;
    src = p.pW2 + (size_t)(nt*16 + (l & 15))*256 + kc*32 + ((l >> 4) << 3);
    dst = p.w2f + (size_t)g3*8;
  }
  float4 v0 = *(const float4*)src;
  float4 v1 = *(const float4*)(src + 4);
  uint4 o;
  o.x = pk2(v0.x, v0.y); o.y = pk2(v0.z, v0.w);
  o.z = pk2(v1.x, v1.y); o.w = pk2(v1.z, v1.w);
  *(uint4*)dst = o;
}

// ---------------- grid barrier (all-poll, no cache invalidation) ----------------
__device__ __forceinline__ void gbar(unsigned int* slots, unsigned int ep){
  __syncthreads();
  if (threadIdx.x == 0){
    coh_stu(&slots[blockIdx.x << 4], ep);
  }
  if (threadIdx.x < 64){
    const int base = threadIdx.x << 2;
    for (;;){
      unsigned int a = coh_ldu(&slots[(base + 0) << 4]);
      unsigned int b = coh_ldu(&slots[(base + 1) << 4]);
      unsigned int c = coh_ldu(&slots[(base + 2) << 4]);
      unsigned int d = coh_ldu(&slots[(base + 3) << 4]);
      bool ok = (a >= ep) & (b >= ep) & (c >= ep) & (d >= ep);
      if (__all(ok)) break;
    }
  }
  asm volatile("" ::: "memory");
  __syncthreads();
}

// ---------------- persistent decoder ----------------
__launch_bounds__(NTHR, 2)
__global__ void k_decoder(DP p){
  extern __shared__ char smem[];
  u16*   wA     = (u16*)smem;                    // 57344 B
  u16*   wC     = (u16*)(smem + 57344);          // 81920 B
  float* bias_l = (float*)(smem + 139264);       // 32 f32
  char*  uni    = smem + 139392;                 // 22848 B phase-union
  float* redA  = (float*)uni;                    // CA: 4 slots x 2mt x 16c x 16b (8192 B)
  float* redC  = (float*)(uni + 8192);           // CA: 5 slots (10240 B)
  float* aw_l  = (float*)uni;                    // B1: [2][288] padded aw/aw_cum (2304 B)
  float* q_l   = (float*)(uni + 2304);           // B1: 16 f32
  float* ah_l  = (float*)(uni + 2368);           // B1: 1024 f32 (4096 B)
  u16*   im2   = (u16*)(uni + 6464);             // B1: 16384 B wave-owned im2col / proj staging
  float* r_l   = (float*)uni;                    // B2: 8 f32
  float* awn_l = (float*)(uni + 64);             // B2: 256 f32

  const int blk = blockIdx.x;
  const int tid = threadIdx.x;
  const int bb = blk & 31, rr = blk >> 5;
  const int w = tid >> 6, l = tid & 63;

  { // load persistent weights into LDS
    const uint4* s  = (const uint4*)(p.wfA + (size_t)blk*56*512);
    uint4* d = (uint4*)wA;
    for (int i2 = tid; i2 < 3584; i2 += NTHR) d[i2] = s[i2];
    const uint4* s2 = (const uint4*)(p.wfC + (size_t)blk*80*512);
    uint4* d2 = (uint4*)wC;
    for (int i2 = tid; i2 < 5120; i2 += NTHR) d2[i2] = s2[i2];
    if (tid < 16){
      int R = ((tid >> 2) << 10) + blk*4 + (tid & 3);
      bias_l[tid] = p.ab[R];
    } else if (tid < 32){
      int c = tid - 16;
      int R = ((c >> 2) << 10) + blk*4 + (c & 3);
      bias_l[tid] = p.db[R];
    }
  }
  __syncthreads();

  const int len = p.lens[bb];
  float att_c = 0.f, dec_c = 0.f;
  unsigned int ep = 0;

  for (int i = 0; i <= 400; ++i){
    const bool hasA = (i < 400), hasC = (i > 0);
    const u16* xd = p.Xdyn + (size_t)(i & 1)*57344;
    const u16* yb = p.Yf + (size_t)((i + 1) & 1)*81920;
    const int cc = l & 15, rg = l >> 4;

    // ===== phase CA: [A(56) | C(80)] = 136 K-chunks, 17 per wave (wave 3 straddles) =====
    if (hasA && w < 3){
      f32x4 acc0 = {0.f,0.f,0.f,0.f}, acc1 = {0.f,0.f,0.f,0.f};
      int c0 = w*17;
      gemm_batch<6>(xd, wA, c0,      l, acc0, acc1);
      gemm_batch<6>(xd, wA, c0 + 6,  l, acc0, acc1);
      gemm_batch<5>(xd, wA, c0 + 12, l, acc0, acc1);
      *(f32x4*)(redA + (((w*2 + 0)*16 + cc) << 4) + (rg << 2)) = acc0;
      *(f32x4*)(redA + (((w*2 + 1)*16 + cc) << 4) + (rg << 2)) = acc1;
    }
    if (w == 3){
      if (hasA){
        f32x4 acc0 = {0.f,0.f,0.f,0.f}, acc1 = {0.f,0.f,0.f,0.f};
        gemm_batch<5>(xd, wA, 51, l, acc0, acc1);
        *(f32x4*)(redA + (((3*2 + 0)*16 + cc) << 4) + (rg << 2)) = acc0;
        *(f32x4*)(redA + (((3*2 + 1)*16 + cc) << 4) + (rg << 2)) = acc1;
      }
      if (hasC){
        f32x4 acc0 = {0.f,0.f,0.f,0.f}, acc1 = {0.f,0.f,0.f,0.f};
        gemm_batch<6>(yb, wC, 0, l, acc0, acc1);
        gemm_batch<6>(yb, wC, 6, l, acc0, acc1);
        *(f32x4*)(redC + (((0*2 + 0)*16 + cc) << 4) + (rg << 2)) = acc0;
        *(f32x4*)(redC + (((0*2 + 1)*16 + cc) << 4) + (rg << 2)) = acc1;
      }
    }
    if (hasC && w >= 4){
      f32x4 acc0 = {0.f,0.f,0.f,0.f}, acc1 = {0.f,0.f,0.f,0.f};
      int c0 = 12 + (w - 4)*17;
      gemm_batch<6>(yb, wC, c0,      l, acc0, acc1);
      gemm_batch<6>(yb, wC, c0 + 6,  l, acc0, acc1);
      gemm_batch<5>(yb, wC, c0 + 12, l, acc0, acc1);
      int slot = w - 3;
      *(f32x4*)(redC + (((slot*2 + 0)*16 + cc) << 4) + (rg << 2)) = acc0;
      *(f32x4*)(redC + (((slot*2 + 1)*16 + cc) << 4) + (rg << 2)) = acc1;
    }
    __syncthreads();
    if (hasA && tid < 128){   // att LSTM update; block owns dims blk*4+d
      int b = tid >> 2, d = tid & 3, mt = b >> 4, b15 = b & 15;
      float gi = bias_l[d], gf = bias_l[4 + d], gg = bias_l[8 + d], go = bias_l[12 + d];
      #pragma unroll
      for (int s2 = 0; s2 < 4; ++s2){
        const float* base = redA + (((s2*2 + mt)*16) << 4) + b15;
        gi += base[(d) << 4]; gf += base[(4 + d) << 4];
        gg += base[(8 + d) << 4]; go += base[(12 + d) << 4];
      }
      att_c = fsigm(gf)*att_c + fsigm(gi)*ftanh(gg);
      float h = fsigm(go)*ftanh(att_c);
      int hidx = blk*4 + d;
      coh_stf(&p.ah[b*1024 + hidx], h);
      unsigned int hv = (unsigned int)f2bf(h);
      unsigned int ov = __shfl_xor(hv, 1, 64);
      if ((d & 1) == 0){
        unsigned int pk = hv | (ov << 16);
        { int k = hidx; int ch = k >> 5, kk = k & 31;
          coh_stu((unsigned int*)&p.Yf[(size_t)(((i & 1)*80 + ch)*2 + mt)*512 + frag_off(b15, kk)], pk); }
        { int k = 768 + hidx; int ch = k >> 5, kk = k & 31;
          coh_stu((unsigned int*)&p.Xdyn[(size_t)((((i + 1) & 1)*56 + ch)*2 + mt)*512 + frag_off(b15, kk)], pk); }
      }
    }
    if (hasC && tid >= 128 && tid < 256){   // dec LSTM update (step i-1)
      int t2 = tid - 128;
      int b = t2 >> 2, d = t2 & 3, mt = b >> 4, b15 = b & 15;
      float gi = bias_l[16 + d], gf = bias_l[16 + 4 + d], gg = bias_l[16 + 8 + d], go = bias_l[16 + 12 + d];
      #pragma unroll
      for (int s2 = 0; s2 < 5; ++s2){
        const float* base = redC + (((s2*2 + mt)*16) << 4) + b15;
        gi += base[(d) << 4]; gf += base[(4 + d) << 4];
        gg += base[(8 + d) << 4]; go += base[(12 + d) << 4];
      }
      dec_c = fsigm(gf)*dec_c + fsigm(gi)*ftanh(gg);
      float h = fsigm(go)*ftanh(dec_c);
      int hidx = blk*4 + d;
      coh_stf(&p.dh[b*1024 + hidx], h);
      unsigned int hv = (unsigned int)f2bf(h);
      unsigned int ov = __shfl_xor(hv, 1, 64);
      if ((d & 1) == 0){
        unsigned int pk = hv | (ov << 16);
        int k = 1536 + hidx; int ch = k >> 5, kk = k & 31;
        coh_stu((unsigned int*)&p.Yf[(size_t)(((i & 1)*80 + ch)*2 + mt)*512 + frag_off(b15, kk)], pk);
      }
    }
    gbar(p.bar, ++ep);

    // ===== phase B1: q + energies (wave-owned im2col) + projection(i-1) =====
    if (hasA){
      for (int s = tid; s < 576; s += NTHR){
        int c = s / 288, o = s - c*288;
        float v2 = 0.f;
        if (o >= 16 && o < 272)
          v2 = c ? coh_ldf(&p.awc[bb*256 + (o - 16)]) : coh_ldf(&p.aw[bb*256 + (o - 16)]);
        aw_l[s] = v2;
      }
      ah_l[tid]       = coh_ldf(&p.ah[bb*1024 + tid]);
      ah_l[512 + tid] = coh_ldf(&p.ah[bb*1024 + 512 + tid]);
      __syncthreads();
      { // q slice for a in [rr*16, rr*16+16)
        int asub = tid >> 5, ksub = tid & 31;
        const float* qwr = p.qW + (size_t)(rr*16 + asub)*1024;
        float s = 0.f;
        #pragma unroll 8
        for (int m = 0; m < 32; ++m){
          int k = ksub + (m << 5);
          s += qwr[k] * ah_l[k];
        }
        s += __shfl_xor(s, 16, 32); s += __shfl_xor(s, 8, 32);
        s += __shfl_xor(s, 4, 32);  s += __shfl_xor(s, 2, 32); s += __shfl_xor(s, 1, 32);
        if (ksub == 0) q_l[asub] = s;
      }
      __syncthreads();
      for (int hh = 0; hh < 2; ++hh){
        // wave-owned im2col: wave w writes exactly the tile its MFMA reads
        #pragma unroll
        for (int t = 0; t < 16; ++t){
          int s = (w << 10) + (t << 6) + l;
          int jj = s & 7, ll = (s >> 3) & 63, kc = (s >> 9) & 1;
          int trow = hh*128 + w*16 + (ll & 15);
          int k = kc*32 + ((ll >> 4) << 3) + jj;
          float v2 = 0.f;
          if (k < 31) v2 = aw_l[1 + trow + k];
          else if (k >= 32 && k < 63) v2 = aw_l[289 + trow + (k - 32)];
          im2[s] = f2bf(v2);
        }
        asm volatile("s_waitcnt lgkmcnt(0)" ::: "memory");
        {
          f32x4 acc = {0.f,0.f,0.f,0.f};
          short8 a0 = *(const short8*)(im2 + ((w*2 + 0)*64 + l)*8);
          short8 b0 = *(const short8*)(p.ckf + (size_t)rr*1024 + (0*64 + l)*8);
          short8 a1 = *(const short8*)(im2 + ((w*2 + 1)*64 + l)*8);
          short8 b1 = *(const short8*)(p.ckf + (size_t)rr*1024 + (1*64 + l)*8);
          acc = __builtin_amdgcn_mfma_f32_16x16x32_bf16(a0, b0, acc, 0, 0, 0);
          acc = __builtin_amdgcn_mfma_f32_16x16x32_bf16(a1, b1, acc, 0, 0, 0);
          int a_l = l & 15;
          float q_a = q_l[a_l];
          float va = p.vW[rr*16 + a_l];
          int tbase = hh*128 + w*16 + rg*4;
          const float* pmr = p.pmT + (size_t)(bb*128 + rr*16 + a_l)*256 + tbase;
          f32x4 pv = *(const f32x4*)pmr;
          float e0 = va * ftanh(acc[0] + q_a + pv[0]);
          float e1 = va * ftanh(acc[1] + q_a + pv[1]);
          float e2 = va * ftanh(acc[2] + q_a + pv[2]);
          float e3 = va * ftanh(acc[3] + q_a + pv[3]);
          #pragma unroll
          for (int msk = 8; msk >= 1; msk >>= 1){
            e0 += __shfl_xor(e0, msk, 16);
            e1 += __shfl_xor(e1, msk, 16);
            e2 += __shfl_xor(e2, msk, 16);
            e3 += __shfl_xor(e3, msk, 16);
          }
          if (a_l == 0){
            union { float f[4]; u64 q[2]; } evv;
            evv.f[0]=e0; evv.f[1]=e1; evv.f[2]=e2; evv.f[3]=e3;
            u64* dst = (u64*)(p.e_buf + (size_t)(bb*8 + rr)*256 + tbase);
            coh_st64(&dst[0], evv.q[0]);
            coh_st64(&dst[1], evv.q[1]);
          }
        }
      }
    }
    if (hasC){   // projection for step i-1
      __syncthreads();                     // im2 region reuse: wait for all energies
      float* sh_f = (float*)im2;
      for (int s = tid; s < 1536; s += NTHR){
        float v = (s < 1024) ? coh_ldf(&p.dh[bb*1024 + s])
                             : coh_ldf(&p.ctx[bb*512 + (s - 1024)]);
        sh_f[s] = v;
      }
      __syncthreads();
      int grp = tid >> 5, gl = tid & 31;
      int cnt = (rr == 7) ? 11 : 10;
      if (grp < cnt){
        int r = rr*10 + grp;
        const float* wrow = (r < 80) ? (p.pjW + (size_t)r*1536) : p.gW;
        float s = 0.f;
        for (int k = gl; k < 1536; k += 32) s += wrow[k] * sh_f[k];
        s += __shfl_xor(s, 16, 32); s += __shfl_xor(s, 8, 32);
        s += __shfl_xor(s, 4, 32);  s += __shfl_xor(s, 2, 32); s += __shfl_xor(s, 1, 32);
        if (gl == 0){
          if (r < 80) p.out_mel[(size_t)(bb*80 + r)*400 + (i - 1)] = s + p.pjb[r];
          else        p.out_gate[bb*400 + (i - 1)] = s + p.gb[0];
        }
      }
    }
    if (i == 400) break;
    gbar(p.bar, ++ep);

    // ===== phase B2: softmax (register-resident) + ctx slice =====
    {
      float s = -3.0e38f, exv = 0.f;
      if (tid < 256){
        float av[8];
        #pragma unroll
        for (int r2 = 0; r2 < 8; ++r2)
          av[r2] = coh_ldf(&p.e_buf[(size_t)(bb*8 + r2)*256 + tid]);
        s = ((av[0]+av[1])+(av[2]+av[3])) + ((av[4]+av[5])+(av[6]+av[7]));
        if (tid >= len) s = -1e9f;
        float mv = s;
        #pragma unroll
        for (int off = 32; off >= 1; off >>= 1) mv = fmaxf(mv, __shfl_xor(mv, off, 64));
        if (l == 0) r_l[w] = mv;
      }
      // copy next step's static-x fragments into Xdyn (8 blocks, 1 u32/thread)
      if (rr == 1 && bb < 8 && i < 399){
        int idx = (bb << 9) | tid;
        unsigned int val = ((const unsigned int*)(p.xfrag + (size_t)(i + 1)*8192))[idx];
        coh_stu((unsigned int*)(p.Xdyn + (size_t)((i + 1) & 1)*57344) + idx, val);
      }
      __syncthreads();
      if (tid < 256){
        float mx = fmaxf(fmaxf(r_l[0], r_l[1]), fmaxf(r_l[2], r_l[3]));
        exv = __expf(s - mx);
        float sv = exv;
        #pragma unroll
        for (int off = 32; off >= 1; off >>= 1) sv += __shfl_xor(sv, off, 64);
        if (l == 0) r_l[4 + w] = sv;
      }
      __syncthreads();
      if (tid < 256){
        float tot = (r_l[4] + r_l[5]) + (r_l[6] + r_l[7]);
        float awn = exv * __fdividef(1.f, tot);
        awn_l[tid] = awn;
        if (rr == 0){
          coh_stf(&p.aw[bb*256 + tid], awn);
          float c0 = coh_ldf(&p.awc[bb*256 + tid]);
          coh_stf(&p.awc[bb*256 + tid], c0 + awn);
          p.out_align[(size_t)(bb*400 + i)*256 + tid] = awn;
        }
      }
      __syncthreads();
      { // ctx slice e' in [rr*64, rr*64+64)
        int el = rr*64 + (tid >> 3), g = tid & 7;
        const float* mr = p.memory + (size_t)bb*256*512 + el;   // read-only: cached
        float s2 = 0.f;
        for (int t2 = g; t2 < 256; t2 += 8) s2 += awn_l[t2] * mr[(size_t)t2*512];
        s2 += __shfl_xor(s2, 4, 8); s2 += __shfl_xor(s2, 2, 8); s2 += __shfl_xor(s2, 1, 8);
        if (g == 0){
          coh_stf(&p.ctx[bb*512 + el], s2);
          unsigned int cv = (unsigned int)f2bf(s2);
          unsigned int ov = __shfl_xor(cv, 8, 64);
          if (((tid >> 3) & 1) == 0){
            unsigned int pk = cv | (ov << 16);
            int mt = bb >> 4, b15 = bb & 15;
            { int k = 1024 + el; int ch = k >> 5, kk = k & 31;
              coh_stu((unsigned int*)&p.Yf[(size_t)(((i & 1)*80 + ch)*2 + mt)*512 + frag_off(b15, kk)], pk); }
            { int k = 256 + el; int ch = k >> 5, kk = k & 31;
              coh_stu((unsigned int*)&p.Xdyn[(size_t)((((i + 1) & 1)*56 + ch)*2 + mt)*512 + frag_off(b15, kk)], pk); }
          }
        }
      }
    }
    gbar(p.bar, ++ep);
  }
}

// ---------------- host ----------------
extern "C" void kernel_launch(void* const* d_in, const int* in_sizes, int n_in,
                              void* d_out, int out_size, void* d_ws, size_t ws_size,
                              hipStream_t stream){
  (void)in_sizes; (void)n_in; (void)out_size; (void)ws_size;
  DP p;
  p.memory = (const float*)d_in[0];
  p.dec_in = (const float*)d_in[1];
  p.lens   = (const int*)d_in[2];
  p.pW1 = (const float*)d_in[3];  p.pW2 = (const float*)d_in[4];
  p.aWi = (const float*)d_in[5];  p.aWh = (const float*)d_in[6];  p.ab = (const float*)d_in[7];
  p.cW  = (const float*)d_in[8];  p.ldW = (const float*)d_in[9];  p.qW = (const float*)d_in[10];
  p.mW  = (const float*)d_in[11]; p.vW  = (const float*)d_in[12];
  p.dWi = (const float*)d_in[13]; p.dWh = (const float*)d_in[14]; p.db = (const float*)d_in[15];
  p.pjW = (const float*)d_in[16]; p.pjb = (const float*)d_in[17];
  p.gW  = (const float*)d_in[18]; p.gb  = (const float*)d_in[19];

  char* ws = (char*)d_ws;
  size_t o = 0;
  auto take = [&](size_t bytes)->char*{ char* r = ws + o; o += (bytes + 255) & ~(size_t)255; return r; };
  p.xfrag = (u16*)take((size_t)3276800*2);
  p.h1f   = (u16*)take((size_t)3276800*2);
  p.w2f   = (u16*)take((size_t)65536*2);
  p.wfA   = (u16*)take((size_t)7340032*2);
  p.wfC   = (u16*)take((size_t)10485760*2);
  p.ckf   = (u16*)take((size_t)8192*2);
  p.pmT   = (float*)take((size_t)1048576*4);
  p.e_buf = (float*)take((size_t)65536*4);
  p.ah    = (float*)take((size_t)32768*4);
  p.dh    = (float*)take((size_t)32768*4);
  p.ctx   = (float*)take((size_t)16384*4);
  char* z0 = ws + o;                     // zero-init region
  p.Xdyn  = (u16*)take((size_t)114688*2);  // 2 x 56 chunks x 2 mt x 512
  p.Yf    = (u16*)take((size_t)163840*2);
  p.aw    = (float*)take((size_t)8192*4);
  p.awc   = (float*)take((size_t)8192*4);
  p.bar   = (unsigned int*)take(256*64);   // 256 epoch slots, 64B apart
  size_t zbytes = (size_t)((ws + o) - z0);

  float* out = (float*)d_out;
  p.out_mel   = out;
  p.out_gate  = out + 1024000;
  p.out_align = out + 1036800;

  hipMemsetAsync(z0, 0, zbytes, stream);
  // order matters: k_h2 consumes w2f (from k_wfrag) and h1f (from k_pre1)
  k_pre1 <<<dim3(12800), dim3(256), 0, stream>>>(p);
  k_wfrag<<<dim3(4368),  dim3(512), 0, stream>>>(p);
  k_ck   <<<dim3(16),    dim3(512), 0, stream>>>(p);
  k_pm   <<<dim3(256),   dim3(512), 0, stream>>>(p);
  k_h2   <<<dim3(800),   dim3(256), 0, stream>>>(p);
  // Xdyn[0] static-x chunks rely on x(t=0)==0 (go-frame zeros, prenet unbiased),
  // so the memset above is the correct step-0 initialization.

  hipFuncSetAttribute(reinterpret_cast<const void*>(k_decoder),
                      hipFuncAttributeMaxDynamicSharedMemorySize, LDS_BYTES);
  DP pp = p;
  void* args[] = { &pp };
  hipError_t err = hipLaunchCooperativeKernel(reinterpret_cast<void*>(k_decoder),
                                              dim3(NBLK), dim3(NTHR), args,
                                              (unsigned int)LDS_BYTES, stream);
  if (err != hipSuccess){
    // co-residency still guaranteed: 256 blocks, ~158KB LDS -> 1 block/CU on 256 CUs
    k_decoder<<<dim3(NBLK), dim3(NTHR), LDS_BYTES, stream>>>(pp);
  }
}